// Round 1
// 32841.919 us; speedup vs baseline: 1.2496x; 1.2496x over previous
//
#include <hip/hip_runtime.h>
#include <math.h>

// Problem constants
#define B_   128
#define T_   20
#define S_   512
#define D_   1024
#define H_   16
#define L_   4
#define KC_  2048   // codebook size
#define DFF_ 4096

typedef __attribute__((ext_vector_type(8))) short bf16x8;   // 8 bf16 (4 VGPRs)
typedef __attribute__((ext_vector_type(4))) float f32x4;

__device__ __forceinline__ unsigned short f2bf_rne(float f) {
    unsigned u = __float_as_uint(f);
    u += 0x7fffu + ((u >> 16) & 1u);
    return (unsigned short)(u >> 16);
}
__device__ __forceinline__ unsigned pack2(float a, float b) {
    return (unsigned)f2bf_rne(a) | ((unsigned)f2bf_rne(b) << 16);
}

// async global->LDS, 16B per lane; LDS dest is wave-uniform base + lane*16
__device__ __forceinline__ void gload16(const unsigned short* g, unsigned short* l)
{
    __builtin_amdgcn_global_load_lds(
        (const __attribute__((address_space(1))) unsigned int*)g,
        (__attribute__((address_space(3))) unsigned int*)l,
        16, 0, 0);
}

// ---------------------------------------------------------------------------
// fp32 GEMM (encoder + VQ path — bit-stable, idx exactness):
// C[M,N] = A[M,K] * W[N,K]^T (+bias)(+bias2)(+relu); M%128==0, N%128==0, K%16==0
// ---------------------------------------------------------------------------
__global__ __launch_bounds__(256, 2)
void gemm_nt(const float* __restrict__ A, int lda,
             const float* __restrict__ W, int ldb,
             float* __restrict__ C, int ldc,
             const float* __restrict__ bias,
             const float* __restrict__ bias2,
             int Kd, int relu)
{
    __shared__ float As[16][132];
    __shared__ float Bs[16][132];
    const int tid = threadIdx.x;
    const int m0 = blockIdx.y << 7;
    const int n0 = blockIdx.x << 7;
    const int tx = tid & 15;
    const int ty = tid >> 4;

    float acc[2][2][4][4];
#pragma unroll
    for (int a = 0; a < 2; ++a)
#pragma unroll
        for (int b = 0; b < 2; ++b)
#pragma unroll
            for (int i = 0; i < 4; ++i)
#pragma unroll
                for (int j = 0; j < 4; ++j) acc[a][b][i][j] = 0.f;

    const int lrow = tid >> 2;
    const int lkk  = (tid & 3) << 2;
    const float* Ap0 = A + (long)(m0 + lrow)      * lda + lkk;
    const float* Ap1 = A + (long)(m0 + lrow + 64) * lda + lkk;
    const float* Bp0 = W + (long)(n0 + lrow)      * ldb + lkk;
    const float* Bp1 = W + (long)(n0 + lrow + 64) * ldb + lkk;

    for (int k0 = 0; k0 < Kd; k0 += 16) {
        const float4 a0 = *(const float4*)(Ap0 + k0);
        const float4 a1 = *(const float4*)(Ap1 + k0);
        const float4 b0 = *(const float4*)(Bp0 + k0);
        const float4 b1 = *(const float4*)(Bp1 + k0);
        __syncthreads();
        As[lkk + 0][lrow] = a0.x; As[lkk + 1][lrow] = a0.y;
        As[lkk + 2][lrow] = a0.z; As[lkk + 3][lrow] = a0.w;
        As[lkk + 0][lrow + 64] = a1.x; As[lkk + 1][lrow + 64] = a1.y;
        As[lkk + 2][lrow + 64] = a1.z; As[lkk + 3][lrow + 64] = a1.w;
        Bs[lkk + 0][lrow] = b0.x; Bs[lkk + 1][lrow] = b0.y;
        Bs[lkk + 2][lrow] = b0.z; Bs[lkk + 3][lrow] = b0.w;
        Bs[lkk + 0][lrow + 64] = b1.x; Bs[lkk + 1][lrow + 64] = b1.y;
        Bs[lkk + 2][lrow + 64] = b1.z; Bs[lkk + 3][lrow + 64] = b1.w;
        __syncthreads();
#pragma unroll
        for (int kk = 0; kk < 16; ++kk) {
            const float4 aLo = *(const float4*)&As[kk][ty << 2];
            const float4 aHi = *(const float4*)&As[kk][(ty << 2) + 64];
            const float4 bLo = *(const float4*)&Bs[kk][tx << 2];
            const float4 bHi = *(const float4*)&Bs[kk][(tx << 2) + 64];
            const float am[2][4] = {{aLo.x, aLo.y, aLo.z, aLo.w},
                                    {aHi.x, aHi.y, aHi.z, aHi.w}};
            const float bn[2][4] = {{bLo.x, bLo.y, bLo.z, bLo.w},
                                    {bHi.x, bHi.y, bHi.z, bHi.w}};
#pragma unroll
            for (int mi = 0; mi < 2; ++mi)
#pragma unroll
                for (int i = 0; i < 4; ++i) {
                    const float av = am[mi][i];
#pragma unroll
                    for (int ni = 0; ni < 2; ++ni) {
                        acc[mi][ni][i][0] += av * bn[ni][0];
                        acc[mi][ni][i][1] += av * bn[ni][1];
                        acc[mi][ni][i][2] += av * bn[ni][2];
                        acc[mi][ni][i][3] += av * bn[ni][3];
                    }
                }
        }
    }

#pragma unroll
    for (int mi = 0; mi < 2; ++mi)
#pragma unroll
        for (int i = 0; i < 4; ++i) {
            const int m = m0 + (mi << 6) + (ty << 2) + i;
            float* crow = C + (long)m * ldc + n0;
#pragma unroll
            for (int ni = 0; ni < 2; ++ni) {
                const int n = (ni << 6) + (tx << 2);
                float4 v = make_float4(acc[mi][ni][i][0], acc[mi][ni][i][1],
                                       acc[mi][ni][i][2], acc[mi][ni][i][3]);
                if (bias) {
                    v.x += bias[n0 + n];     v.y += bias[n0 + n + 1];
                    v.z += bias[n0 + n + 2]; v.w += bias[n0 + n + 3];
                }
                if (bias2) {
                    v.x += bias2[n0 + n];     v.y += bias2[n0 + n + 1];
                    v.z += bias2[n0 + n + 2]; v.w += bias2[n0 + n + 3];
                }
                if (relu) {
                    v.x = fmaxf(v.x, 0.f); v.y = fmaxf(v.y, 0.f);
                    v.z = fmaxf(v.z, 0.f); v.w = fmaxf(v.w, 0.f);
                }
                *(float4*)(crow + n) = v;
            }
        }
}

// ---------------------------------------------------------------------------
// bf16 MFMA GEMM v3 (decoder): m97-structure.
// C[M,N] = A_bf16[M,K] * Wbf16[N,K]^T. 128x128 tile, BK=64, 4 waves (each a
// 64x64 sub-tile = 4x4 frags of 16x16x32), LINEAR LDS, global_load_lds w=16
// for both A and B (no VALU repack: A is pre-converted bf16).
// Split-K: grid.z slices of ksl K-elems, fp32 atomicAdd epilogue, slice 0
// carries bias; C must be zeroed when splitk>1; relu/Cb only when splitk==1.
// M%128==0, N%128==0, ksl%64==0, lda/ldb %8==0 (16B-aligned rows).
// Fragment + C/D layouts per learn_hip m89/m91 (same as the verified v2).
// ---------------------------------------------------------------------------
__global__ __launch_bounds__(256, 2)
void gemm_bf16_lds(const unsigned short* __restrict__ A, int lda,
                   const unsigned short* __restrict__ W, int ldb,
                   float* __restrict__ Cf, int ldc,
                   unsigned short* __restrict__ Cb, int ldcb,
                   const float* __restrict__ bias,
                   const float* __restrict__ bias2,
                   int ksl, int splitk, int relu)
{
    __shared__ __align__(16) unsigned short As[128 * 64];
    __shared__ __align__(16) unsigned short Bs[128 * 64];
    const int tid  = threadIdx.x;
    const int wave = tid >> 6;
    const int lane = tid & 63;
    const int m0 = blockIdx.y << 7;
    const int n0 = blockIdx.x << 7;
    const int kbeg = blockIdx.z * ksl;
    const int wm = (wave >> 1) << 6;    // 0 / 64
    const int wn = (wave & 1) << 6;     // 0 / 64
    const int lrow = lane & 15;
    const int q = lane >> 4;

    // staging: issue i of wave w covers tile bytes [(w*4+i)*1024, +1024)
    // tile row = byte/128 (64 bf16 cols * 2B), lane l contributes bytes l*16
    const unsigned short* Ag[4];
    const unsigned short* Wg[4];
    unsigned short* Al[4];
    unsigned short* Bl[4];
#pragma unroll
    for (int i = 0; i < 4; ++i) {
        const int blk = (wave << 2) + i;          // 0..15
        const int bo  = (blk << 10) + (lane << 4);
        const int r   = bo >> 7;
        const int ce  = (bo & 127) >> 1;
        Ag[i] = A + (long)(m0 + r) * lda + kbeg + ce;
        Wg[i] = W + (long)(n0 + r) * ldb + kbeg + ce;
        Al[i] = As + (blk << 9);                  // wave-uniform LDS base
        Bl[i] = Bs + (blk << 9);
    }

    f32x4 acc[4][4];
#pragma unroll
    for (int i = 0; i < 4; ++i)
#pragma unroll
        for (int j = 0; j < 4; ++j) acc[i][j] = (f32x4){0.f, 0.f, 0.f, 0.f};

    for (int k0 = 0; k0 < ksl; k0 += 64) {
        __syncthreads();                          // prev compute done w/ LDS
#pragma unroll
        for (int i = 0; i < 4; ++i) gload16(Ag[i] + k0, Al[i]);
#pragma unroll
        for (int i = 0; i < 4; ++i) gload16(Wg[i] + k0, Bl[i]);
        __syncthreads();                          // implies vmcnt(0) drain

#pragma unroll
        for (int kk = 0; kk < 2; ++kk) {
            bf16x8 af[4], bfr[4];
#pragma unroll
            for (int mi = 0; mi < 4; ++mi)
                af[mi] = *(const bf16x8*)&As[(wm + mi * 16 + lrow) * 64 + kk * 32 + q * 8];
#pragma unroll
            for (int ni = 0; ni < 4; ++ni)
                bfr[ni] = *(const bf16x8*)&Bs[(wn + ni * 16 + lrow) * 64 + kk * 32 + q * 8];
#pragma unroll
            for (int mi = 0; mi < 4; ++mi)
#pragma unroll
                for (int ni = 0; ni < 4; ++ni)
                    acc[mi][ni] = __builtin_amdgcn_mfma_f32_16x16x32_bf16(
                        af[mi], bfr[ni], acc[mi][ni], 0, 0, 0);
        }
    }

    // C/D layout: col = lane&15, row = (lane>>4)*4 + reg   [m89/m91]
    const int addb = (blockIdx.z == 0);
#pragma unroll
    for (int mi = 0; mi < 4; ++mi) {
#pragma unroll
        for (int r = 0; r < 4; ++r) {
            const int m = m0 + wm + mi * 16 + q * 4 + r;
            const long crow = (long)m * ldc;
#pragma unroll
            for (int ni = 0; ni < 4; ++ni) {
                const int n = n0 + wn + ni * 16 + lrow;
                float v = acc[mi][ni][r];
                if (splitk == 1) {
                    if (bias)  v += bias[n];
                    if (bias2) v += bias2[n];
                    if (relu)  v = fmaxf(v, 0.f);
                    if (Cf) Cf[crow + n] = v;
                    if (Cb) Cb[(long)m * ldcb + n] = f2bf_rne(v);
                } else {
                    if (addb) {
                        if (bias)  v += bias[n];
                        if (bias2) v += bias2[n];
                    }
                    atomicAdd(Cf + crow + n, v);
                }
            }
        }
    }
}

// zero a strided MxN fp32 region (ldc != N); one block per row, float4/thread
__global__ void zero2d(float* __restrict__ C, int ldc)
{
    *(float4*)(C + (long)blockIdx.x * ldc + (threadIdx.x << 2)) =
        make_float4(0.f, 0.f, 0.f, 0.f);
}

// fp32 -> bf16 (RNE) bulk convert; n4 = n/4 float4 groups
__global__ __launch_bounds__(256)
void convert_f2bf(const float* __restrict__ src, unsigned short* __restrict__ dst, long n4)
{
    const long i = (long)blockIdx.x * 256 + threadIdx.x;
    if (i < n4) {
        const float4 v = ((const float4*)src)[i];
        uint2 o;
        o.x = pack2(v.x, v.y);
        o.y = pack2(v.z, v.w);
        ((uint2*)dst)[i] = o;
    }
}

// strided fp32 -> bf16 row convert (optional relu); grid = rows, 256 thr
__global__ __launch_bounds__(256)
void convert2d_f2bf(const float* __restrict__ src, int lds,
                    unsigned short* __restrict__ dst, int ldd,
                    int cols, int relu)
{
    const int r = blockIdx.x;
    const float* s = src + (long)r * lds;
    unsigned short* d = dst + (long)r * ldd;
    for (int c = threadIdx.x << 2; c < cols; c += 1024) {
        float4 v = *(const float4*)(s + c);
        if (relu) {
            v.x = fmaxf(v.x, 0.f); v.y = fmaxf(v.y, 0.f);
            v.z = fmaxf(v.z, 0.f); v.w = fmaxf(v.w, 0.f);
        }
        uint2 o; o.x = pack2(v.x, v.y); o.y = pack2(v.z, v.w);
        *(uint2*)(d + c) = o;
    }
}

// ---------------------------------------------------------------------------
// Attention for hd=64: one wave per (b, h, query-pos). nkeys <= 20.
// Writes fp32 (opf) and/or bf16 (opb) output, same strides.
// ---------------------------------------------------------------------------
__global__ __launch_bounds__(64)
void attn64(const float* __restrict__ qp, const float* __restrict__ kp,
            const float* __restrict__ vp, float* __restrict__ opf,
            unsigned short* __restrict__ opb,
            int H, long q_bs, long q_ts, long kv_bs, long kv_ts,
            long o_bs, long o_ts, int nk, int causal, float scale)
{
    const int b  = blockIdx.x / H;
    const int h  = blockIdx.x % H;
    const int qj = blockIdx.y;
    const int tid = threadIdx.x;
    __shared__ float sc[32];

    const float qv = qp[(long)b * q_bs + (long)qj * q_ts + h * 64 + tid];
    const int nkeys = causal ? (qj + 1) : nk;
    const long kbase = (long)b * kv_bs + h * 64 + tid;

    for (int j = 0; j < nkeys; ++j) {
        float p = qv * kp[kbase + (long)j * kv_ts];
#pragma unroll
        for (int off = 32; off >= 1; off >>= 1) p += __shfl_xor(p, off);
        if (tid == 0) sc[j] = p * scale;
    }
    __syncthreads();

    const float sval = (tid < nkeys) ? sc[tid] : -INFINITY;
    float mx = sval;
#pragma unroll
    for (int off = 32; off >= 1; off >>= 1) mx = fmaxf(mx, __shfl_xor(mx, off));
    const float e = (tid < nkeys) ? expf(sval - mx) : 0.f;
    float ssum = e;
#pragma unroll
    for (int off = 32; off >= 1; off >>= 1) ssum += __shfl_xor(ssum, off);
    if (tid < nkeys) sc[tid] = e / ssum;
    __syncthreads();

    float acc = 0.f;
    for (int j = 0; j < nkeys; ++j) acc += sc[j] * vp[kbase + (long)j * kv_ts];
    const long ob = (long)b * o_bs + (long)qj * o_ts + h * 64 + tid;
    if (opf) opf[ob] = acc;
    if (opb) opb[ob] = f2bf_rne(acc);
}

// ---------------------------------------------------------------------------
// LayerNorm with residual; optional bf16 mirror (ob)
// ---------------------------------------------------------------------------
__global__ __launch_bounds__(256)
void ln_res(const float* __restrict__ x, const float* __restrict__ hh,
            const float* __restrict__ g, const float* __restrict__ bta,
            float* __restrict__ out, unsigned short* __restrict__ ob)
{
    __shared__ float red[4];
    const int r = blockIdx.x, tid = threadIdx.x;
    const long base = (long)r * D_ + (tid << 2);
    const float4 xv = *(const float4*)(x + base);
    const float4 hv = *(const float4*)(hh + base);
    const float v0 = xv.x + hv.x, v1 = xv.y + hv.y, v2 = xv.z + hv.z, v3 = xv.w + hv.w;

    float s = v0 + v1 + v2 + v3;
#pragma unroll
    for (int off = 32; off >= 1; off >>= 1) s += __shfl_xor(s, off);
    const int wid = tid >> 6, lane = tid & 63;
    if (lane == 0) red[wid] = s;
    __syncthreads();
    const float mean = (red[0] + red[1] + red[2] + red[3]) * (1.f / D_);
    __syncthreads();

    const float d0 = v0 - mean, d1 = v1 - mean, d2 = v2 - mean, d3 = v3 - mean;
    float s2 = d0 * d0 + d1 * d1 + d2 * d2 + d3 * d3;
#pragma unroll
    for (int off = 32; off >= 1; off >>= 1) s2 += __shfl_xor(s2, off);
    if (lane == 0) red[wid] = s2;
    __syncthreads();
    const float var = (red[0] + red[1] + red[2] + red[3]) * (1.f / D_);
    const float rs = 1.f / sqrtf(var + 1e-5f);

    const float4 gv = *(const float4*)(g + (tid << 2));
    const float4 bv = *(const float4*)(bta + (tid << 2));
    float4 o;
    o.x = d0 * rs * gv.x + bv.x; o.y = d1 * rs * gv.y + bv.y;
    o.z = d2 * rs * gv.z + bv.z; o.w = d3 * rs * gv.w + bv.w;
    *(float4*)(out + base) = o;
    if (ob) {
        uint2 ov; ov.x = pack2(o.x, o.y); ov.y = pack2(o.z, o.w);
        *(uint2*)(ob + base) = ov;
    }
}

__global__ void embed_add(const float* __restrict__ se, const int* __restrict__ actions,
                          const float* __restrict__ act_emb, const float* __restrict__ pos,
                          float* __restrict__ x)
{
    const int r = blockIdx.x, c = threadIdx.x << 2;
    const int t = r % T_;
    const int a = actions[r];
    const float4 sv = *(const float4*)(se + (long)r * D_ + c);
    const float4 av = *(const float4*)(act_emb + (long)a * D_ + c);
    const float4 pv = *(const float4*)(pos + (long)t * D_ + c);
    float4 o;
    o.x = sv.x + av.x + pv.x; o.y = sv.y + av.y + pv.y;
    o.z = sv.z + av.z + pv.z; o.w = sv.w + av.w + pv.w;
    *(float4*)(x + (long)r * D_ + c) = o;
}

__global__ void cur0_init(const float* __restrict__ se, const float* __restrict__ pos,
                          float* __restrict__ cur)
{
    const int b = blockIdx.x, c = threadIdx.x << 2;
    const long base = (long)b * T_ * D_ + c;
    const float4 sv = *(const float4*)(se + base);
    const float4 pv = *(const float4*)(pos + c);
    float4 o; o.x = sv.x + pv.x; o.y = sv.y + pv.y; o.z = sv.z + pv.z; o.w = sv.w + pv.w;
    *(float4*)(cur + base) = o;
}

__global__ void assemble_y(const float* __restrict__ cur, float* __restrict__ y,
                           unsigned short* __restrict__ yb, int P)
{
    const int r = blockIdx.x;
    const int b = r / P, j = r - b * P;
    const int c = threadIdx.x << 2;
    const float4 v = *(const float4*)(cur + ((long)b * T_ + j) * D_ + c);
    *(float4*)(y + (long)r * D_ + c) = v;
    uint2 o; o.x = pack2(v.x, v.y); o.y = pack2(v.z, v.w);
    *(uint2*)(yb + (long)r * D_ + c) = o;
}

__global__ void quant_build(const int* __restrict__ idx, const float* __restrict__ cb,
                            float* __restrict__ quant, unsigned short* __restrict__ qb)
{
    const int r = blockIdx.x, c = threadIdx.x << 2;
    const int code = idx[r];
    const float4 v = *(const float4*)(cb + (long)code * D_ + c);
    *(float4*)(quant + (long)r * D_ + c) = v;
    uint2 o; o.x = pack2(v.x, v.y); o.y = pack2(v.z, v.w);
    *(uint2*)(qb + (long)r * D_ + c) = o;
}

__global__ __launch_bounds__(256)
void row_sumsq(const float* __restrict__ A, float* __restrict__ out)
{
    __shared__ float red[4];
    const int r = blockIdx.x, tid = threadIdx.x;
    const float4 v = *(const float4*)(A + (long)r * D_ + (tid << 2));
    float s = v.x * v.x + v.y * v.y + v.z * v.z + v.w * v.w;
#pragma unroll
    for (int off = 32; off >= 1; off >>= 1) s += __shfl_xor(s, off);
    const int wid = tid >> 6, lane = tid & 63;
    if (lane == 0) red[wid] = s;
    __syncthreads();
    if (tid == 0) out[r] = red[0] + red[1] + red[2] + red[3];
}

__global__ __launch_bounds__(256)
void vq_argmin(const float* __restrict__ x, const float* __restrict__ dot,
               const float* __restrict__ c2, int* __restrict__ idx_i,
               float* __restrict__ idx_f)
{
    __shared__ float red[4];
    __shared__ float redv[4];
    __shared__ int   redi[4];
    const int r = blockIdx.x, tid = threadIdx.x;
    const float4 v = *(const float4*)(x + (long)r * D_ + (tid << 2));
    float s = v.x * v.x + v.y * v.y + v.z * v.z + v.w * v.w;
#pragma unroll
    for (int off = 32; off >= 1; off >>= 1) s += __shfl_xor(s, off);
    const int wid = tid >> 6, lane = tid & 63;
    if (lane == 0) red[wid] = s;
    __syncthreads();
    const float a = red[0] + red[1] + red[2] + red[3];

    float best = 3.4e38f; int bidx = 0;
    const float* dr = dot + (long)r * KC_;
    for (int j = tid; j < KC_; j += 256) {
        const float d = (a - 2.f * dr[j]) + c2[j];
        if (d < best) { best = d; bidx = j; }
    }
#pragma unroll
    for (int off = 32; off >= 1; off >>= 1) {
        const float ob = __shfl_xor(best, off);
        const int   oi = __shfl_xor(bidx, off);
        if (ob < best || (ob == best && oi < bidx)) { best = ob; bidx = oi; }
    }
    if (lane == 0) { redv[wid] = best; redi[wid] = bidx; }
    __syncthreads();
    if (tid == 0) {
        for (int w2 = 1; w2 < 4; ++w2)
            if (redv[w2] < best || (redv[w2] == best && redi[w2] < bidx)) {
                best = redv[w2]; bidx = redi[w2];
            }
        idx_i[r] = bidx;
        idx_f[r] = (float)bidx;
    }
}

__global__ void zero_f(float* p) { p[0] = 0.f; }

__global__ __launch_bounds__(256)
void sq_diff_partial(const float* __restrict__ x, const float* __restrict__ q,
                     float* __restrict__ accum)
{
    __shared__ float red[4];
    const int r = blockIdx.x, tid = threadIdx.x;
    const long base = (long)r * D_ + (tid << 2);
    const float4 xv = *(const float4*)(x + base);
    const float4 qv = *(const float4*)(q + base);
    const float d0 = xv.x - qv.x, d1 = xv.y - qv.y, d2 = xv.z - qv.z, d3 = xv.w - qv.w;
    float s = d0 * d0 + d1 * d1 + d2 * d2 + d3 * d3;
#pragma unroll
    for (int off = 32; off >= 1; off >>= 1) s += __shfl_xor(s, off);
    const int wid = tid >> 6, lane = tid & 63;
    if (lane == 0) red[wid] = s;
    __syncthreads();
    if (tid == 0) atomicAdd(accum, red[0] + red[1] + red[2] + red[3]);
}

__global__ void loss_final(const float* __restrict__ accum, float* __restrict__ out)
{
    out[0] = 2.f * accum[0] * (1.f / (float)((long)B_ * T_ * D_));
}

// ---------------------------------------------------------------------------
extern "C" void kernel_launch(void* const* d_in, const int* in_sizes, int n_in,
                              void* d_out, int out_size, void* d_ws, size_t ws_size,
                              hipStream_t stream)
{
    const float* states      = (const float*)d_in[0];
    const int*   actions     = (const int*)  d_in[1];
    const float* enc_W       = (const float*)d_in[2];
    const float* enc_b       = (const float*)d_in[3];
    const float* act_emb     = (const float*)d_in[4];
    const float* pos_emb     = (const float*)d_in[5];
    const float* enc_qkv_w   = (const float*)d_in[6];
    const float* enc_qkv_b   = (const float*)d_in[7];
    const float* enc_out_w   = (const float*)d_in[8];
    const float* enc_out_b   = (const float*)d_in[9];
    const float* enc_ln1_g   = (const float*)d_in[10];
    const float* enc_ln1_b   = (const float*)d_in[11];
    const float* enc_ln2_g   = (const float*)d_in[12];
    const float* enc_ln2_b   = (const float*)d_in[13];
    const float* enc_ff1_w   = (const float*)d_in[14];
    const float* enc_ff1_b   = (const float*)d_in[15];
    const float* enc_ff2_w   = (const float*)d_in[16];
    const float* enc_ff2_b   = (const float*)d_in[17];
    const float* dec_sa_qkv_w= (const float*)d_in[18];
    const float* dec_sa_qkv_b= (const float*)d_in[19];
    const float* dec_sa_out_w= (const float*)d_in[20];
    const float* dec_sa_out_b= (const float*)d_in[21];
    const float* dec_ca_qkv_w= (const float*)d_in[22];
    const float* dec_ca_qkv_b= (const float*)d_in[23];
    const float* dec_ca_out_w= (const float*)d_in[24];
    const float* dec_ca_out_b= (const float*)d_in[25];
    const float* dec_ln1_g   = (const float*)d_in[26];
    const float* dec_ln1_b   = (const float*)d_in[27];
    const float* dec_ln2_g   = (const float*)d_in[28];
    const float* dec_ln2_b   = (const float*)d_in[29];
    const float* dec_ln3_g   = (const float*)d_in[30];
    const float* dec_ln3_b   = (const float*)d_in[31];
    const float* dec_ff1_w   = (const float*)d_in[32];
    const float* dec_ff1_b   = (const float*)d_in[33];
    const float* dec_ff2_w   = (const float*)d_in[34];
    const float* dec_ff2_b   = (const float*)d_in[35];
    const float* codebook    = (const float*)d_in[36];
    const float* rec_W       = (const float*)d_in[37];
    const float* rec_b       = (const float*)d_in[38];

    float* out      = (float*)d_out;
    float* pred     = out;                              // [128, 19, 512]
    float* loss_out = out + (long)B_ * (T_ - 1) * S_;
    float* idx_out  = loss_out + 1;

    const long NTOK = (long)B_ * T_;                    // 2560
    const long ROW  = NTOK * D_;

    float* w    = (float*)d_ws;
    float* se   = w;  w += ROW;
    float* xbuf = w;  w += ROW;                         // also ybuf (decoder phase)
    float* big  = w;  w += NTOK * DFF_;
    float* bufa = w;  w += ROW;
    float* bufb = w;  w += ROW;
    float* quant= w;  w += ROW;
    float* cur  = w;  w += ROW;
    float* memKV= w;  w += (long)L_ * NTOK * 2 * D_;
    float* c2   = w;  w += KC_;
    float* accum= w;  w += 1;
    int*   idx_i= (int*)w;
    float* ybuf = xbuf;                                 // phase-disjoint alias

    // bf16 weight mirrors (decoder path) + bf16 activation mirrors
    unsigned short* wb = (unsigned short*)(idx_i + NTOK);
    unsigned short* wb_sa_qkv = wb;  wb += (long)L_ * 3 * D_ * D_;
    unsigned short* wb_sa_out = wb;  wb += (long)L_ * D_ * D_;
    unsigned short* wb_ca_qkv = wb;  wb += (long)L_ * 3 * D_ * D_;
    unsigned short* wb_ca_out = wb;  wb += (long)L_ * D_ * D_;
    unsigned short* wb_ff1    = wb;  wb += (long)L_ * DFF_ * D_;
    unsigned short* wb_ff2    = wb;  wb += (long)L_ * D_ * DFF_;
    unsigned short* wb_rec    = wb;  wb += (long)S_ * D_;
    unsigned short* wb_enc    = wb;  wb += (long)D_ * S_;
    unsigned short* bf_y      = wb;  wb += ROW;          // ybuf mirror
    unsigned short* bf_a      = wb;  wb += ROW;          // attn-out mirror
    unsigned short* bf_big    = wb;  wb += NTOK * DFF_;  // ff1-out mirror
    unsigned short* bf_q      = wb;  wb += ROW;          // quant mirror
    unsigned short* bf_p      = wb;  wb += (long)B_ * S_;// pred-step mirror
    const size_t need = (size_t)((char*)wb - (char*)d_ws);
    if (ws_size < need) return;  // fail loudly (output stays poisoned)

    auto gemm = [&](const float* A, int lda, const float* Wt, int Kd, int N, int M,
                    float* C, int ldc, const float* bias, const float* bias2, int relu) {
        dim3 g(N >> 7, M >> 7);
        gemm_nt<<<g, 256, 0, stream>>>(A, lda, Wt, Kd, C, ldc, bias, bias2, Kd, relu);
    };
    // bf16 m97-structure GEMM, adaptive split-K.
    // needf: fp32 C required by consumer/output; Cb: optional bf16 mirror.
    // strided: 1 -> zero via zero2d (ldc != N).
    auto gemmL = [&](const unsigned short* Abf, long lda, const unsigned short* Wt,
                     int Kd, int N, int M, float* Cf, int ldc, int needf,
                     unsigned short* Cb, int ldcb,
                     const float* bias, const float* bias2, int relu, int strided) {
        const long base = (long)(M >> 7) * (N >> 7);
        int sk = 1;
        while (sk < 16) {
            const int nx = sk << 1;
            if (Kd % (64 * nx)) break;
            if (base * sk >= 256) break;
            sk = nx;
        }
        if (sk > 1) {
            if (strided) zero2d<<<M, N >> 2, 0, stream>>>(Cf, ldc);
            else hipMemsetAsync(Cf, 0, (size_t)M * N * sizeof(float), stream);
        }
        float* Cfk = (sk == 1 && !needf && Cb) ? nullptr : Cf;
        unsigned short* Cbk = (sk == 1) ? Cb : nullptr;
        dim3 g(N >> 7, M >> 7, sk);
        gemm_bf16_lds<<<g, 256, 0, stream>>>(Abf, (int)lda, Wt, Kd, Cfk, ldc,
                                             Cbk, ldcb, bias, bias2,
                                             Kd / sk, sk, relu);
        if (sk > 1 && Cb)
            convert2d_f2bf<<<M, 256, 0, stream>>>(Cf, ldc, Cb, ldcb, N, relu);
    };
    auto attn = [&](const float* qp, const float* kp, const float* vp,
                    float* opf, unsigned short* opb,
                    long q_bs, long q_ts, long kv_bs, long kv_ts,
                    long o_bs, long o_ts, int nq, int nk, int causal) {
        dim3 g(B_ * H_, nq);
        attn64<<<g, 64, 0, stream>>>(qp, kp, vp, opf, opb, H_, q_bs, q_ts, kv_bs, kv_ts,
                                     o_bs, o_ts, nk, causal, 0.125f);
    };
    auto conv = [&](const float* s, unsigned short* d, long n) {
        const long n4 = n >> 2;
        convert_f2bf<<<(int)((n4 + 255) >> 8), 256, 0, stream>>>(s, d, n4);
    };

    // ---- weight conversions (decoder path only) ----
    conv(dec_sa_qkv_w, wb_sa_qkv, (long)L_ * 3 * D_ * D_);
    conv(dec_sa_out_w, wb_sa_out, (long)L_ * D_ * D_);
    conv(dec_ca_qkv_w, wb_ca_qkv, (long)L_ * 3 * D_ * D_);
    conv(dec_ca_out_w, wb_ca_out, (long)L_ * D_ * D_);
    conv(dec_ff1_w,    wb_ff1,    (long)L_ * DFF_ * D_);
    conv(dec_ff2_w,    wb_ff2,    (long)L_ * D_ * DFF_);
    conv(rec_W,        wb_rec,    (long)S_ * D_);
    conv(enc_W,        wb_enc,    (long)D_ * S_);

    // ======================= Encoder (fp32 — idx exactness) =======================
    gemm(states, S_, enc_W, S_, D_, (int)NTOK, se, D_, enc_b, nullptr, 0);
    embed_add<<<(int)NTOK, 256, 0, stream>>>(se, actions, act_emb, pos_emb, xbuf);

    for (int i = 0; i < L_; ++i) {
        gemm(xbuf, D_, enc_qkv_w + (long)i * 3 * D_ * D_, D_, 3 * D_, (int)NTOK,
             big, 3 * D_, enc_qkv_b + (long)i * 3 * D_, nullptr, 0);
        attn(big, big + D_, big + 2 * D_, bufa, nullptr,
             (long)T_ * 3 * D_, 3 * D_, (long)T_ * 3 * D_, 3 * D_,
             (long)T_ * D_, D_, T_, T_, 0);
        gemm(bufa, D_, enc_out_w + (long)i * D_ * D_, D_, D_, (int)NTOK,
             bufb, D_, enc_out_b + i * D_, nullptr, 0);
        ln_res<<<(int)NTOK, 256, 0, stream>>>(xbuf, bufb, enc_ln1_g + i * D_, enc_ln1_b + i * D_, xbuf, nullptr);
        gemm(xbuf, D_, enc_ff1_w + (long)i * DFF_ * D_, D_, DFF_, (int)NTOK,
             big, DFF_, enc_ff1_b + i * DFF_, nullptr, 1);
        gemm(big, DFF_, enc_ff2_w + (long)i * D_ * DFF_, DFF_, D_, (int)NTOK,
             bufb, D_, enc_ff2_b + i * D_, nullptr, 0);
        ln_res<<<(int)NTOK, 256, 0, stream>>>(xbuf, bufb, enc_ln2_g + i * D_, enc_ln2_b + i * D_, xbuf, nullptr);
    }

    // ======================= VQ (fp32, numpy order) =======================
    row_sumsq<<<KC_, 256, 0, stream>>>(codebook, c2);
    gemm(xbuf, D_, codebook, D_, KC_, (int)NTOK, big, KC_, nullptr, nullptr, 0);
    vq_argmin<<<(int)NTOK, 256, 0, stream>>>(xbuf, big, c2, idx_i, idx_out);
    quant_build<<<(int)NTOK, 256, 0, stream>>>(idx_i, codebook, quant, bf_q);
    zero_f<<<1, 1, 0, stream>>>(accum);
    sq_diff_partial<<<(int)NTOK, 256, 0, stream>>>(xbuf, quant, accum);
    loss_final<<<1, 1, 0, stream>>>(accum, loss_out);

    // ============ Decoder: precompute cross-attn K/V (bf16 MFMA) ============
    for (int i = 0; i < L_; ++i) {
        const unsigned short* wkv = wb_ca_qkv + (long)i * 3 * D_ * D_ + (long)D_ * D_;
        const float* bkv = dec_ca_qkv_b + (long)i * 3 * D_ + D_;
        gemmL(bf_q, D_, wkv, D_, 2 * D_, (int)NTOK,
              memKV + (long)i * NTOK * 2 * D_, 2 * D_, 1, nullptr, 0,
              bkv, nullptr, 0, 0);
    }
    cur0_init<<<B_, 256, 0, stream>>>(se, pos_emb, cur);

    // ============ Decoder: 19 autoregressive steps (bf16 m97 GEMMs) ============
    for (int t = 0; t < T_ - 1; ++t) {
        const int P = t + 1;
        const int M = B_ * P;
        assemble_y<<<M, 256, 0, stream>>>(cur, ybuf, bf_y, P);

        for (int i = 0; i < L_; ++i) {
            // --- causal self-attention ---
            gemmL(bf_y, D_, wb_sa_qkv + (long)i * 3 * D_ * D_, D_, 3 * D_, M,
                  big, 3 * D_, 1, nullptr, 0,
                  dec_sa_qkv_b + (long)i * 3 * D_, nullptr, 0, 0);
            attn(big, big + D_, big + 2 * D_, nullptr, bf_a,
                 (long)P * 3 * D_, 3 * D_, (long)P * 3 * D_, 3 * D_,
                 (long)P * D_, D_, P, P, 1);
            gemmL(bf_a, D_, wb_sa_out + (long)i * D_ * D_, D_, D_, M,
                  bufb, D_, 1, nullptr, 0, dec_sa_out_b + i * D_, nullptr, 0, 0);
            ln_res<<<M, 256, 0, stream>>>(ybuf, bufb, dec_ln1_g + i * D_, dec_ln1_b + i * D_, ybuf, bf_y);

            // --- cross-attention (memory fixed -> precomputed memKV) ---
            gemmL(bf_y, D_, wb_ca_qkv + (long)i * 3 * D_ * D_, D_, D_, M,
                  bufa, D_, 1, nullptr, 0, dec_ca_qkv_b + (long)i * 3 * D_, nullptr, 0, 0);
            const float* mkv = memKV + (long)i * NTOK * 2 * D_;
            attn(bufa, mkv, mkv + D_, nullptr, bf_a,
                 (long)P * D_, D_, (long)T_ * 2 * D_, 2 * D_,
                 (long)P * D_, D_, P, P, 0);
            gemmL(bf_a, D_, wb_ca_out + (long)i * D_ * D_, D_, D_, M,
                  bufb, D_, 1, nullptr, 0, dec_ca_out_b + i * D_, nullptr, 0, 0);
            ln_res<<<M, 256, 0, stream>>>(ybuf, bufb, dec_ln2_g + i * D_, dec_ln2_b + i * D_, ybuf, bf_y);

            // --- FFN (relu folded into ff1 epilogue / convert; ff2 reads bf16) ---
            gemmL(bf_y, D_, wb_ff1 + (long)i * DFF_ * D_, D_, DFF_, M,
                  big, DFF_, 0, bf_big, DFF_,
                  dec_ff1_b + i * DFF_, nullptr, 1, 0);
            gemmL(bf_big, DFF_, wb_ff2 + (long)i * D_ * DFF_, DFF_, D_, M,
                  bufb, D_, 1, nullptr, 0, dec_ff2_b + i * D_, nullptr, 0, 0);
            ln_res<<<M, 256, 0, stream>>>(ybuf, bufb, dec_ln3_g + i * D_, dec_ln3_b + i * D_, ybuf, bf_y);
        }

        // preds[t] = y[:, -1] @ rec_W^T + rec_b  -> pred[:, t, :]  (strided C)
        gemmL(bf_y + (long)(P - 1) * D_, (long)P * D_, wb_rec, D_, S_, B_,
              pred + (long)t * S_, (T_ - 1) * S_, 1,
              (t < T_ - 2) ? bf_p : nullptr, S_,
              rec_b, nullptr, 0, 1);

        // dec_in[:, t+1] = preds[t] @ enc_W^T + enc_b + pos_emb[t+1]  (strided C)
        if (t < T_ - 2)
            gemmL(bf_p, S_, wb_enc, S_, D_, B_,
                  cur + (long)(t + 1) * D_, T_ * D_, 1, nullptr, 0,
                  enc_b, pos_emb + (long)(t + 1) * D_, 0, 1);
    }
}

// Round 2
// 20994.699 us; speedup vs baseline: 1.9547x; 1.5643x over previous
//
#include <hip/hip_runtime.h>
#include <math.h>

// Problem constants
#define B_   128
#define T_   20
#define S_   512
#define D_   1024
#define H_   16
#define L_   4
#define KC_  2048   // codebook size
#define DFF_ 4096

typedef __attribute__((ext_vector_type(8))) short bf16x8;   // 8 bf16 (4 VGPRs)
typedef __attribute__((ext_vector_type(4))) float f32x4;

__device__ __forceinline__ unsigned short f2bf_rne(float f) {
    unsigned u = __float_as_uint(f);
    u += 0x7fffu + ((u >> 16) & 1u);
    return (unsigned short)(u >> 16);
}
__device__ __forceinline__ unsigned pack2(float a, float b) {
    return (unsigned)f2bf_rne(a) | ((unsigned)f2bf_rne(b) << 16);
}

// async global->LDS, 16B per lane; LDS dest is wave-uniform base + lane*16
__device__ __forceinline__ void gload16(const unsigned short* g, unsigned short* l)
{
    __builtin_amdgcn_global_load_lds(
        (const __attribute__((address_space(1))) unsigned int*)g,
        (__attribute__((address_space(3))) unsigned int*)l,
        16, 0, 0);
}

// ---------------------------------------------------------------------------
// fp32 GEMM (encoder + VQ path — bit-stable, idx exactness):
// C[M,N] = A[M,K] * W[N,K]^T (+bias)(+bias2)(+relu); M%128==0, N%128==0, K%16==0
// ---------------------------------------------------------------------------
__global__ __launch_bounds__(256, 2)
void gemm_nt(const float* __restrict__ A, int lda,
             const float* __restrict__ W, int ldb,
             float* __restrict__ C, int ldc,
             const float* __restrict__ bias,
             const float* __restrict__ bias2,
             int Kd, int relu)
{
    __shared__ float As[16][132];
    __shared__ float Bs[16][132];
    const int tid = threadIdx.x;
    const int m0 = blockIdx.y << 7;
    const int n0 = blockIdx.x << 7;
    const int tx = tid & 15;
    const int ty = tid >> 4;

    float acc[2][2][4][4];
#pragma unroll
    for (int a = 0; a < 2; ++a)
#pragma unroll
        for (int b = 0; b < 2; ++b)
#pragma unroll
            for (int i = 0; i < 4; ++i)
#pragma unroll
                for (int j = 0; j < 4; ++j) acc[a][b][i][j] = 0.f;

    const int lrow = tid >> 2;
    const int lkk  = (tid & 3) << 2;
    const float* Ap0 = A + (long)(m0 + lrow)      * lda + lkk;
    const float* Ap1 = A + (long)(m0 + lrow + 64) * lda + lkk;
    const float* Bp0 = W + (long)(n0 + lrow)      * ldb + lkk;
    const float* Bp1 = W + (long)(n0 + lrow + 64) * ldb + lkk;

    for (int k0 = 0; k0 < Kd; k0 += 16) {
        const float4 a0 = *(const float4*)(Ap0 + k0);
        const float4 a1 = *(const float4*)(Ap1 + k0);
        const float4 b0 = *(const float4*)(Bp0 + k0);
        const float4 b1 = *(const float4*)(Bp1 + k0);
        __syncthreads();
        As[lkk + 0][lrow] = a0.x; As[lkk + 1][lrow] = a0.y;
        As[lkk + 2][lrow] = a0.z; As[lkk + 3][lrow] = a0.w;
        As[lkk + 0][lrow + 64] = a1.x; As[lkk + 1][lrow + 64] = a1.y;
        As[lkk + 2][lrow + 64] = a1.z; As[lkk + 3][lrow + 64] = a1.w;
        Bs[lkk + 0][lrow] = b0.x; Bs[lkk + 1][lrow] = b0.y;
        Bs[lkk + 2][lrow] = b0.z; Bs[lkk + 3][lrow] = b0.w;
        Bs[lkk + 0][lrow + 64] = b1.x; Bs[lkk + 1][lrow + 64] = b1.y;
        Bs[lkk + 2][lrow + 64] = b1.z; Bs[lkk + 3][lrow + 64] = b1.w;
        __syncthreads();
#pragma unroll
        for (int kk = 0; kk < 16; ++kk) {
            const float4 aLo = *(const float4*)&As[kk][ty << 2];
            const float4 aHi = *(const float4*)&As[kk][(ty << 2) + 64];
            const float4 bLo = *(const float4*)&Bs[kk][tx << 2];
            const float4 bHi = *(const float4*)&Bs[kk][(tx << 2) + 64];
            const float am[2][4] = {{aLo.x, aLo.y, aLo.z, aLo.w},
                                    {aHi.x, aHi.y, aHi.z, aHi.w}};
            const float bn[2][4] = {{bLo.x, bLo.y, bLo.z, bLo.w},
                                    {bHi.x, bHi.y, bHi.z, bHi.w}};
#pragma unroll
            for (int mi = 0; mi < 2; ++mi)
#pragma unroll
                for (int i = 0; i < 4; ++i) {
                    const float av = am[mi][i];
#pragma unroll
                    for (int ni = 0; ni < 2; ++ni) {
                        acc[mi][ni][i][0] += av * bn[ni][0];
                        acc[mi][ni][i][1] += av * bn[ni][1];
                        acc[mi][ni][i][2] += av * bn[ni][2];
                        acc[mi][ni][i][3] += av * bn[ni][3];
                    }
                }
        }
    }

#pragma unroll
    for (int mi = 0; mi < 2; ++mi)
#pragma unroll
        for (int i = 0; i < 4; ++i) {
            const int m = m0 + (mi << 6) + (ty << 2) + i;
            float* crow = C + (long)m * ldc + n0;
#pragma unroll
            for (int ni = 0; ni < 2; ++ni) {
                const int n = (ni << 6) + (tx << 2);
                float4 v = make_float4(acc[mi][ni][i][0], acc[mi][ni][i][1],
                                       acc[mi][ni][i][2], acc[mi][ni][i][3]);
                if (bias) {
                    v.x += bias[n0 + n];     v.y += bias[n0 + n + 1];
                    v.z += bias[n0 + n + 2]; v.w += bias[n0 + n + 3];
                }
                if (bias2) {
                    v.x += bias2[n0 + n];     v.y += bias2[n0 + n + 1];
                    v.z += bias2[n0 + n + 2]; v.w += bias2[n0 + n + 3];
                }
                if (relu) {
                    v.x = fmaxf(v.x, 0.f); v.y = fmaxf(v.y, 0.f);
                    v.z = fmaxf(v.z, 0.f); v.w = fmaxf(v.w, 0.f);
                }
                *(float4*)(crow + n) = v;
            }
        }
}

// ---------------------------------------------------------------------------
// bf16 MFMA GEMM (m97-structure): C[M,N] = A_bf16[M,K] * Wbf16[N,K]^T
// 128x128 tile, BK=64, 4 waves, linear LDS, global_load_lds w=16.
// pmode=1: store raw fp32 partial of K-slice z at Cf + z*pstride + m*ldc + n
//          (bias/relu applied later in reduce_*). grid.z = sk slices of ksl.
// pmode=0: (grid.z==1) direct epilogue: +bias(+bias2)(+relu), write Cf and/or
//          bf16 Cb.
// M%128==0, N%128==0, ksl%64==0, lda/ldb %8 (16B rows).
// Fragment + C/D layouts per learn_hip m89/m91 (verified rounds 1-2).
// ---------------------------------------------------------------------------
__global__ __launch_bounds__(256, 2)
void gemm_bf16_lds(const unsigned short* __restrict__ A, int lda,
                   const unsigned short* __restrict__ W, int ldb,
                   float* __restrict__ Cf, int ldc, long pstride,
                   unsigned short* __restrict__ Cb, int ldcb,
                   const float* __restrict__ bias,
                   const float* __restrict__ bias2,
                   int ksl, int relu, int pmode)
{
    __shared__ __align__(16) unsigned short As[128 * 64];
    __shared__ __align__(16) unsigned short Bs[128 * 64];
    const int tid  = threadIdx.x;
    const int wave = tid >> 6;
    const int lane = tid & 63;
    const int m0 = blockIdx.y << 7;
    const int n0 = blockIdx.x << 7;
    const int kbeg = blockIdx.z * ksl;
    const int wm = (wave >> 1) << 6;    // 0 / 64
    const int wn = (wave & 1) << 6;     // 0 / 64
    const int lrow = lane & 15;
    const int q = lane >> 4;

    const unsigned short* Ag[4];
    const unsigned short* Wg[4];
    unsigned short* Al[4];
    unsigned short* Bl[4];
#pragma unroll
    for (int i = 0; i < 4; ++i) {
        const int blk = (wave << 2) + i;          // 0..15
        const int bo  = (blk << 10) + (lane << 4);
        const int r   = bo >> 7;
        const int ce  = (bo & 127) >> 1;
        Ag[i] = A + (long)(m0 + r) * lda + kbeg + ce;
        Wg[i] = W + (long)(n0 + r) * ldb + kbeg + ce;
        Al[i] = As + (blk << 9);                  // wave-uniform LDS base
        Bl[i] = Bs + (blk << 9);
    }

    f32x4 acc[4][4];
#pragma unroll
    for (int i = 0; i < 4; ++i)
#pragma unroll
        for (int j = 0; j < 4; ++j) acc[i][j] = (f32x4){0.f, 0.f, 0.f, 0.f};

    for (int k0 = 0; k0 < ksl; k0 += 64) {
        __syncthreads();
#pragma unroll
        for (int i = 0; i < 4; ++i) gload16(Ag[i] + k0, Al[i]);
#pragma unroll
        for (int i = 0; i < 4; ++i) gload16(Wg[i] + k0, Bl[i]);
        __syncthreads();

#pragma unroll
        for (int kk = 0; kk < 2; ++kk) {
            bf16x8 af[4], bfr[4];
#pragma unroll
            for (int mi = 0; mi < 4; ++mi)
                af[mi] = *(const bf16x8*)&As[(wm + mi * 16 + lrow) * 64 + kk * 32 + q * 8];
#pragma unroll
            for (int ni = 0; ni < 4; ++ni)
                bfr[ni] = *(const bf16x8*)&Bs[(wn + ni * 16 + lrow) * 64 + kk * 32 + q * 8];
#pragma unroll
            for (int mi = 0; mi < 4; ++mi)
#pragma unroll
                for (int ni = 0; ni < 4; ++ni)
                    acc[mi][ni] = __builtin_amdgcn_mfma_f32_16x16x32_bf16(
                        af[mi], bfr[ni], acc[mi][ni], 0, 0, 0);
        }
    }

    // C/D layout: col = lane&15, row = (lane>>4)*4 + reg   [m89/m91]
    if (pmode) {
        float* pbase = Cf + (long)blockIdx.z * pstride;
#pragma unroll
        for (int mi = 0; mi < 4; ++mi) {
#pragma unroll
            for (int r = 0; r < 4; ++r) {
                const int m = m0 + wm + mi * 16 + q * 4 + r;
                float* crow = pbase + (long)m * ldc;
#pragma unroll
                for (int ni = 0; ni < 4; ++ni)
                    crow[n0 + wn + ni * 16 + lrow] = acc[mi][ni][r];
            }
        }
    } else {
#pragma unroll
        for (int mi = 0; mi < 4; ++mi) {
#pragma unroll
            for (int r = 0; r < 4; ++r) {
                const int m = m0 + wm + mi * 16 + q * 4 + r;
#pragma unroll
                for (int ni = 0; ni < 4; ++ni) {
                    const int n = n0 + wn + ni * 16 + lrow;
                    float v = acc[mi][ni][r];
                    if (bias)  v += bias[n];
                    if (bias2) v += bias2[n];
                    if (relu)  v = fmaxf(v, 0.f);
                    if (Cf) Cf[(long)m * ldc + n] = v;
                    if (Cb) Cb[(long)m * ldcb + n] = f2bf_rne(v);
                }
            }
        }
    }
}

// ---------------------------------------------------------------------------
// reduce_eps: sum sk partial slices + bias(+bias2)(+relu) -> fp32/bf16 dests.
// grid.x = M rows, 256 threads, 4 cols/thread/iter.
// Alias-safe in-place: dF may equal slice 0 of Pt (same pld) — each thread
// reads all slices for its cols before writing.
// ---------------------------------------------------------------------------
__global__ __launch_bounds__(256)
void reduce_eps(const float* __restrict__ Pt, long pstride, int sk, int pld,
                int ncols,
                const float* __restrict__ bias, const float* __restrict__ bias2,
                int relu,
                float* __restrict__ dF, long ldF,
                unsigned short* __restrict__ dB, long ldB)
{
    const int r = blockIdx.x;
    const float* pr = Pt + (long)r * pld;
    for (int c = (threadIdx.x << 2); c < ncols; c += 1024) {
        float4 s = *(const float4*)(pr + c);
        for (int z = 1; z < sk; ++z) {
            const float4 v = *(const float4*)(pr + (long)z * pstride + c);
            s.x += v.x; s.y += v.y; s.z += v.z; s.w += v.w;
        }
        if (bias) {
            const float4 b = *(const float4*)(bias + c);
            s.x += b.x; s.y += b.y; s.z += b.z; s.w += b.w;
        }
        if (bias2) {
            const float4 b = *(const float4*)(bias2 + c);
            s.x += b.x; s.y += b.y; s.z += b.z; s.w += b.w;
        }
        if (relu) {
            s.x = fmaxf(s.x, 0.f); s.y = fmaxf(s.y, 0.f);
            s.z = fmaxf(s.z, 0.f); s.w = fmaxf(s.w, 0.f);
        }
        if (dF) *(float4*)(dF + (long)r * ldF + c) = s;
        if (dB) {
            uint2 o; o.x = pack2(s.x, s.y); o.y = pack2(s.z, s.w);
            *(uint2*)(dB + (long)r * ldB + c) = o;
        }
    }
}

// ---------------------------------------------------------------------------
// reduce_ln: sum sk partial slices (pld=1024) + bias, add residual row,
// LayerNorm(D=1024) with gamma/beta, write fp32 + bf16.
// ---------------------------------------------------------------------------
__global__ __launch_bounds__(256)
void reduce_ln(const float* __restrict__ Pt, long pstride, int sk,
               const float* __restrict__ bias,
               const float* __restrict__ resid, long ldres,
               const float* __restrict__ g, const float* __restrict__ bta,
               float* __restrict__ outF, long ldoF,
               unsigned short* __restrict__ outB, long ldoB)
{
    __shared__ float red[4];
    const int r = blockIdx.x, tid = threadIdx.x;
    const int c = tid << 2;
    const float* pr = Pt + (long)r * 1024 + c;
    float4 s = *(const float4*)pr;
    for (int z = 1; z < sk; ++z) {
        const float4 v = *(const float4*)(pr + (long)z * pstride);
        s.x += v.x; s.y += v.y; s.z += v.z; s.w += v.w;
    }
    const float4 bb = *(const float4*)(bias + c);
    const float4 rv = *(const float4*)(resid + (long)r * ldres + c);
    const float v0 = s.x + bb.x + rv.x, v1 = s.y + bb.y + rv.y;
    const float v2 = s.z + bb.z + rv.z, v3 = s.w + bb.w + rv.w;

    float sm = v0 + v1 + v2 + v3;
#pragma unroll
    for (int off = 32; off >= 1; off >>= 1) sm += __shfl_xor(sm, off);
    const int wid = tid >> 6, lane = tid & 63;
    if (lane == 0) red[wid] = sm;
    __syncthreads();
    const float mean = (red[0] + red[1] + red[2] + red[3]) * (1.f / D_);
    __syncthreads();

    const float d0 = v0 - mean, d1 = v1 - mean, d2 = v2 - mean, d3 = v3 - mean;
    float s2 = d0 * d0 + d1 * d1 + d2 * d2 + d3 * d3;
#pragma unroll
    for (int off = 32; off >= 1; off >>= 1) s2 += __shfl_xor(s2, off);
    if (lane == 0) red[wid] = s2;
    __syncthreads();
    const float var = (red[0] + red[1] + red[2] + red[3]) * (1.f / D_);
    const float rs = 1.f / sqrtf(var + 1e-5f);

    const float4 gv = *(const float4*)(g + c);
    const float4 bv = *(const float4*)(bta + c);
    float4 o;
    o.x = d0 * rs * gv.x + bv.x; o.y = d1 * rs * gv.y + bv.y;
    o.z = d2 * rs * gv.z + bv.z; o.w = d3 * rs * gv.w + bv.w;
    *(float4*)(outF + (long)r * ldoF + c) = o;
    uint2 ov; ov.x = pack2(o.x, o.y); ov.y = pack2(o.z, o.w);
    *(uint2*)(outB + (long)r * ldoB + c) = ov;
}

// fp32 -> bf16 (RNE) bulk convert; n4 = n/4 float4 groups
__global__ __launch_bounds__(256)
void convert_f2bf(const float* __restrict__ src, unsigned short* __restrict__ dst, long n4)
{
    const long i = (long)blockIdx.x * 256 + threadIdx.x;
    if (i < n4) {
        const float4 v = ((const float4*)src)[i];
        uint2 o;
        o.x = pack2(v.x, v.y);
        o.y = pack2(v.z, v.w);
        ((uint2*)dst)[i] = o;
    }
}

// ---------------------------------------------------------------------------
// Attention for hd=64: one wave per (b, h, query-pos). nkeys <= 20.
// Writes fp32 (opf) and/or bf16 (opb) output, same strides.
// ---------------------------------------------------------------------------
__global__ __launch_bounds__(64)
void attn64(const float* __restrict__ qp, const float* __restrict__ kp,
            const float* __restrict__ vp, float* __restrict__ opf,
            unsigned short* __restrict__ opb,
            int H, long q_bs, long q_ts, long kv_bs, long kv_ts,
            long o_bs, long o_ts, int nk, int causal, float scale)
{
    const int b  = blockIdx.x / H;
    const int h  = blockIdx.x % H;
    const int qj = blockIdx.y;
    const int tid = threadIdx.x;
    __shared__ float sc[32];

    const float qv = qp[(long)b * q_bs + (long)qj * q_ts + h * 64 + tid];
    const int nkeys = causal ? (qj + 1) : nk;
    const long kbase = (long)b * kv_bs + h * 64 + tid;

    for (int j = 0; j < nkeys; ++j) {
        float p = qv * kp[kbase + (long)j * kv_ts];
#pragma unroll
        for (int off = 32; off >= 1; off >>= 1) p += __shfl_xor(p, off);
        if (tid == 0) sc[j] = p * scale;
    }
    __syncthreads();

    const float sval = (tid < nkeys) ? sc[tid] : -INFINITY;
    float mx = sval;
#pragma unroll
    for (int off = 32; off >= 1; off >>= 1) mx = fmaxf(mx, __shfl_xor(mx, off));
    const float e = (tid < nkeys) ? expf(sval - mx) : 0.f;
    float ssum = e;
#pragma unroll
    for (int off = 32; off >= 1; off >>= 1) ssum += __shfl_xor(ssum, off);
    if (tid < nkeys) sc[tid] = e / ssum;
    __syncthreads();

    float acc = 0.f;
    for (int j = 0; j < nkeys; ++j) acc += sc[j] * vp[kbase + (long)j * kv_ts];
    const long ob = (long)b * o_bs + (long)qj * o_ts + h * 64 + tid;
    if (opf) opf[ob] = acc;
    if (opb) opb[ob] = f2bf_rne(acc);
}

// ---------------------------------------------------------------------------
// LayerNorm with residual (encoder path); optional bf16 mirror (ob)
// ---------------------------------------------------------------------------
__global__ __launch_bounds__(256)
void ln_res(const float* __restrict__ x, const float* __restrict__ hh,
            const float* __restrict__ g, const float* __restrict__ bta,
            float* __restrict__ out, unsigned short* __restrict__ ob)
{
    __shared__ float red[4];
    const int r = blockIdx.x, tid = threadIdx.x;
    const long base = (long)r * D_ + (tid << 2);
    const float4 xv = *(const float4*)(x + base);
    const float4 hv = *(const float4*)(hh + base);
    const float v0 = xv.x + hv.x, v1 = xv.y + hv.y, v2 = xv.z + hv.z, v3 = xv.w + hv.w;

    float s = v0 + v1 + v2 + v3;
#pragma unroll
    for (int off = 32; off >= 1; off >>= 1) s += __shfl_xor(s, off);
    const int wid = tid >> 6, lane = tid & 63;
    if (lane == 0) red[wid] = s;
    __syncthreads();
    const float mean = (red[0] + red[1] + red[2] + red[3]) * (1.f / D_);
    __syncthreads();

    const float d0 = v0 - mean, d1 = v1 - mean, d2 = v2 - mean, d3 = v3 - mean;
    float s2 = d0 * d0 + d1 * d1 + d2 * d2 + d3 * d3;
#pragma unroll
    for (int off = 32; off >= 1; off >>= 1) s2 += __shfl_xor(s2, off);
    if (lane == 0) red[wid] = s2;
    __syncthreads();
    const float var = (red[0] + red[1] + red[2] + red[3]) * (1.f / D_);
    const float rs = 1.f / sqrtf(var + 1e-5f);

    const float4 gv = *(const float4*)(g + (tid << 2));
    const float4 bv = *(const float4*)(bta + (tid << 2));
    float4 o;
    o.x = d0 * rs * gv.x + bv.x; o.y = d1 * rs * gv.y + bv.y;
    o.z = d2 * rs * gv.z + bv.z; o.w = d3 * rs * gv.w + bv.w;
    *(float4*)(out + base) = o;
    if (ob) {
        uint2 ov; ov.x = pack2(o.x, o.y); ov.y = pack2(o.z, o.w);
        *(uint2*)(ob + base) = ov;
    }
}

__global__ void embed_add(const float* __restrict__ se, const int* __restrict__ actions,
                          const float* __restrict__ act_emb, const float* __restrict__ pos,
                          float* __restrict__ x)
{
    const int r = blockIdx.x, c = threadIdx.x << 2;
    const int t = r % T_;
    const int a = actions[r];
    const float4 sv = *(const float4*)(se + (long)r * D_ + c);
    const float4 av = *(const float4*)(act_emb + (long)a * D_ + c);
    const float4 pv = *(const float4*)(pos + (long)t * D_ + c);
    float4 o;
    o.x = sv.x + av.x + pv.x; o.y = sv.y + av.y + pv.y;
    o.z = sv.z + av.z + pv.z; o.w = sv.w + av.w + pv.w;
    *(float4*)(x + (long)r * D_ + c) = o;
}

__global__ void cur0_init(const float* __restrict__ se, const float* __restrict__ pos,
                          float* __restrict__ cur)
{
    const int b = blockIdx.x, c = threadIdx.x << 2;
    const long base = (long)b * T_ * D_ + c;
    const float4 sv = *(const float4*)(se + base);
    const float4 pv = *(const float4*)(pos + c);
    float4 o; o.x = sv.x + pv.x; o.y = sv.y + pv.y; o.z = sv.z + pv.z; o.w = sv.w + pv.w;
    *(float4*)(cur + base) = o;
}

__global__ void assemble_y(const float* __restrict__ cur, float* __restrict__ y,
                           unsigned short* __restrict__ yb, int P)
{
    const int r = blockIdx.x;
    const int b = r / P, j = r - b * P;
    const int c = threadIdx.x << 2;
    const float4 v = *(const float4*)(cur + ((long)b * T_ + j) * D_ + c);
    *(float4*)(y + (long)r * D_ + c) = v;
    uint2 o; o.x = pack2(v.x, v.y); o.y = pack2(v.z, v.w);
    *(uint2*)(yb + (long)r * D_ + c) = o;
}

// gather last position per batch: ysm[b] = y[b*P + P-1]
__global__ void gather_last(const float* __restrict__ y, int P,
                            float* __restrict__ ysm, unsigned short* __restrict__ ybsm)
{
    const int b = blockIdx.x, c = threadIdx.x << 2;
    const float4 v = *(const float4*)(y + ((long)b * P + (P - 1)) * D_ + c);
    *(float4*)(ysm + (long)b * D_ + c) = v;
    uint2 o; o.x = pack2(v.x, v.y); o.y = pack2(v.z, v.w);
    *(uint2*)(ybsm + (long)b * D_ + c) = o;
}

__global__ void quant_build(const int* __restrict__ idx, const float* __restrict__ cb,
                            float* __restrict__ quant, unsigned short* __restrict__ qb)
{
    const int r = blockIdx.x, c = threadIdx.x << 2;
    const int code = idx[r];
    const float4 v = *(const float4*)(cb + (long)code * D_ + c);
    *(float4*)(quant + (long)r * D_ + c) = v;
    uint2 o; o.x = pack2(v.x, v.y); o.y = pack2(v.z, v.w);
    *(uint2*)(qb + (long)r * D_ + c) = o;
}

__global__ __launch_bounds__(256)
void row_sumsq(const float* __restrict__ A, float* __restrict__ out)
{
    __shared__ float red[4];
    const int r = blockIdx.x, tid = threadIdx.x;
    const float4 v = *(const float4*)(A + (long)r * D_ + (tid << 2));
    float s = v.x * v.x + v.y * v.y + v.z * v.z + v.w * v.w;
#pragma unroll
    for (int off = 32; off >= 1; off >>= 1) s += __shfl_xor(s, off);
    const int wid = tid >> 6, lane = tid & 63;
    if (lane == 0) red[wid] = s;
    __syncthreads();
    if (tid == 0) out[r] = red[0] + red[1] + red[2] + red[3];
}

__global__ __launch_bounds__(256)
void vq_argmin(const float* __restrict__ x, const float* __restrict__ dot,
               const float* __restrict__ c2, int* __restrict__ idx_i,
               float* __restrict__ idx_f)
{
    __shared__ float red[4];
    __shared__ float redv[4];
    __shared__ int   redi[4];
    const int r = blockIdx.x, tid = threadIdx.x;
    const float4 v = *(const float4*)(x + (long)r * D_ + (tid << 2));
    float s = v.x * v.x + v.y * v.y + v.z * v.z + v.w * v.w;
#pragma unroll
    for (int off = 32; off >= 1; off >>= 1) s += __shfl_xor(s, off);
    const int wid = tid >> 6, lane = tid & 63;
    if (lane == 0) red[wid] = s;
    __syncthreads();
    const float a = red[0] + red[1] + red[2] + red[3];

    float best = 3.4e38f; int bidx = 0;
    const float* dr = dot + (long)r * KC_;
    for (int j = tid; j < KC_; j += 256) {
        const float d = (a - 2.f * dr[j]) + c2[j];
        if (d < best) { best = d; bidx = j; }
    }
#pragma unroll
    for (int off = 32; off >= 1; off >>= 1) {
        const float ob = __shfl_xor(best, off);
        const int   oi = __shfl_xor(bidx, off);
        if (ob < best || (ob == best && oi < bidx)) { best = ob; bidx = oi; }
    }
    if (lane == 0) { redv[wid] = best; redi[wid] = bidx; }
    __syncthreads();
    if (tid == 0) {
        for (int w2 = 1; w2 < 4; ++w2)
            if (redv[w2] < best || (redv[w2] == best && redi[w2] < bidx)) {
                best = redv[w2]; bidx = redi[w2];
            }
        idx_i[r] = bidx;
        idx_f[r] = (float)bidx;
    }
}

__global__ void zero_f(float* p) { p[0] = 0.f; }

__global__ __launch_bounds__(256)
void sq_diff_partial(const float* __restrict__ x, const float* __restrict__ q,
                     float* __restrict__ accum)
{
    __shared__ float red[4];
    const int r = blockIdx.x, tid = threadIdx.x;
    const long base = (long)r * D_ + (tid << 2);
    const float4 xv = *(const float4*)(x + base);
    const float4 qv = *(const float4*)(q + base);
    const float d0 = xv.x - qv.x, d1 = xv.y - qv.y, d2 = xv.z - qv.z, d3 = xv.w - qv.w;
    float s = d0 * d0 + d1 * d1 + d2 * d2 + d3 * d3;
#pragma unroll
    for (int off = 32; off >= 1; off >>= 1) s += __shfl_xor(s, off);
    const int wid = tid >> 6, lane = tid & 63;
    if (lane == 0) red[wid] = s;
    __syncthreads();
    if (tid == 0) atomicAdd(accum, red[0] + red[1] + red[2] + red[3]);
}

__global__ void loss_final(const float* __restrict__ accum, float* __restrict__ out)
{
    out[0] = 2.f * accum[0] * (1.f / (float)((long)B_ * T_ * D_));
}

// ---------------------------------------------------------------------------
extern "C" void kernel_launch(void* const* d_in, const int* in_sizes, int n_in,
                              void* d_out, int out_size, void* d_ws, size_t ws_size,
                              hipStream_t stream)
{
    const float* states      = (const float*)d_in[0];
    const int*   actions     = (const int*)  d_in[1];
    const float* enc_W       = (const float*)d_in[2];
    const float* enc_b       = (const float*)d_in[3];
    const float* act_emb     = (const float*)d_in[4];
    const float* pos_emb     = (const float*)d_in[5];
    const float* enc_qkv_w   = (const float*)d_in[6];
    const float* enc_qkv_b   = (const float*)d_in[7];
    const float* enc_out_w   = (const float*)d_in[8];
    const float* enc_out_b   = (const float*)d_in[9];
    const float* enc_ln1_g   = (const float*)d_in[10];
    const float* enc_ln1_b   = (const float*)d_in[11];
    const float* enc_ln2_g   = (const float*)d_in[12];
    const float* enc_ln2_b   = (const float*)d_in[13];
    const float* enc_ff1_w   = (const float*)d_in[14];
    const float* enc_ff1_b   = (const float*)d_in[15];
    const float* enc_ff2_w   = (const float*)d_in[16];
    const float* enc_ff2_b   = (const float*)d_in[17];
    const float* dec_sa_qkv_w= (const float*)d_in[18];
    const float* dec_sa_qkv_b= (const float*)d_in[19];
    const float* dec_sa_out_w= (const float*)d_in[20];
    const float* dec_sa_out_b= (const float*)d_in[21];
    const float* dec_ca_qkv_w= (const float*)d_in[22];
    const float* dec_ca_qkv_b= (const float*)d_in[23];
    const float* dec_ca_out_w= (const float*)d_in[24];
    const float* dec_ca_out_b= (const float*)d_in[25];
    const float* dec_ln1_g   = (const float*)d_in[26];
    const float* dec_ln1_b   = (const float*)d_in[27];
    const float* dec_ln2_g   = (const float*)d_in[28];
    const float* dec_ln2_b   = (const float*)d_in[29];
    const float* dec_ln3_g   = (const float*)d_in[30];
    const float* dec_ln3_b   = (const float*)d_in[31];
    const float* dec_ff1_w   = (const float*)d_in[32];
    const float* dec_ff1_b   = (const float*)d_in[33];
    const float* dec_ff2_w   = (const float*)d_in[34];
    const float* dec_ff2_b   = (const float*)d_in[35];
    const float* codebook    = (const float*)d_in[36];
    const float* rec_W       = (const float*)d_in[37];
    const float* rec_b       = (const float*)d_in[38];

    float* out      = (float*)d_out;
    float* pred     = out;                              // [128, 19, 512]
    float* loss_out = out + (long)B_ * (T_ - 1) * S_;
    float* idx_out  = loss_out + 1;

    const long NTOK = (long)B_ * T_;                    // 2560
    const long ROW  = NTOK * D_;                        // 2621440 floats

    // ---------------- workspace layout ----------------
    // Region R (shared encoder/decoder scratch): 9*ROW/... = 23592960 floats
    float* R    = (float*)d_ws;
    float* xbuf = R;                         // [0, ROW)           enc x / dec ybuf
    float* big  = R + ROW;                   // [ROW, ROW+10.49M)  qkv/ff1/VQ-dot
    float* dq   = big + NTOK * DFF_;         // 2621440            enc bufa / dec q
    float* dscr = dq + ROW;                  // 7864320            enc bufb|quant|se
    float* enc_bufb = dscr;
    float* quant    = dscr + ROW;
    float* se       = dscr + 2 * ROW;
    float* ysm  = dq + (long)2432 * 1024;    // 131072 floats (tail of dq, decoder only)
    float* Rend = dscr + 3 * ROW;            // end of R

    float* cur  = Rend;                      // [B,T,D]
    float* memKV= cur + ROW;                 // L*NTOK*2D
    float* c2   = memKV + (long)L_ * NTOK * 2 * D_;
    float* accum= c2 + KC_;
    int*   idx_i= (int*)(accum + 1);
    float* ybuf = xbuf;

    const long BIGCAP  = NTOK * DFF_;        // 10485760 floats
    const long DSCRCAP = 3 * ROW;            // 7864320 floats

    // bf16 weights + activation mirrors
    unsigned short* wb = (unsigned short*)(idx_i + NTOK);
    unsigned short* wb_sa_qkv = wb;  wb += (long)L_ * 3 * D_ * D_;
    unsigned short* wb_sa_out = wb;  wb += (long)L_ * D_ * D_;
    unsigned short* wb_ca_qkv = wb;  wb += (long)L_ * 3 * D_ * D_;
    unsigned short* wb_ca_out = wb;  wb += (long)L_ * D_ * D_;
    unsigned short* wb_ff1    = wb;  wb += (long)L_ * DFF_ * D_;
    unsigned short* wb_ff2    = wb;  wb += (long)L_ * D_ * DFF_;
    unsigned short* wb_rec    = wb;  wb += (long)S_ * D_;
    unsigned short* wb_enc    = wb;  wb += (long)D_ * S_;
    unsigned short* bf_y      = wb;  wb += ROW;          // ybuf mirror
    unsigned short* bf_a      = wb;  wb += ROW;          // attn-out mirror
    unsigned short* bf_big    = wb;  wb += NTOK * DFF_;  // ff1-out mirror
    unsigned short* bf_q      = wb;  wb += ROW;          // quant mirror
    unsigned short* bf_p      = wb;  wb += (long)B_ * S_;// pred-step mirror
    unsigned short* bf_ysm    = wb;  wb += (long)B_ * D_;// last-pos mirror
    const size_t need = (size_t)((char*)wb - (char*)d_ws);
    if (ws_size < need) return;  // fail loudly (output stays poisoned)

    auto gemm = [&](const float* A, int lda, const float* Wt, int Kd, int N, int M,
                    float* C, int ldc, const float* bias, const float* bias2, int relu) {
        dim3 g(N >> 7, M >> 7);
        gemm_nt<<<g, 256, 0, stream>>>(A, lda, Wt, Kd, C, ldc, bias, bias2, Kd, relu);
    };
    auto pick_sk = [&](int M, int N, int Kd, long cap) {
        const long base = (long)(M >> 7) * (N >> 7);
        int sk = 1;
        while (sk < 16) {
            const int nx = sk << 1;
            if (Kd % (64 * nx)) break;
            if (base * sk >= 256) break;
            if ((long)nx * M * N > cap) break;
            sk = nx;
        }
        return sk;
    };
    // EPS site: GEMM (+bias[,bias2,relu]) -> fp32 dF and/or bf16 dB
    auto site_eps = [&](const unsigned short* A, long lda, const unsigned short* Wt,
                        int Kd, int N, int M, float* part, long cap,
                        float* dF, long ldF, unsigned short* dB, long ldB,
                        const float* bias, const float* bias2, int relu) {
        const int sk = pick_sk(M, N, Kd, cap);
        dim3 g(N >> 7, M >> 7, sk);
        if (sk == 1) {
            gemm_bf16_lds<<<g, 256, 0, stream>>>(A, (int)lda, Wt, Kd,
                dF, (int)ldF, 0, dB, (int)ldB, bias, bias2, Kd, relu, 0);
        } else {
            const long ps = (long)M * N;
            gemm_bf16_lds<<<g, 256, 0, stream>>>(A, (int)lda, Wt, Kd,
                part, N, ps, nullptr, 0, nullptr, nullptr, Kd / sk, 0, 1);
            reduce_eps<<<M, 256, 0, stream>>>(part, ps, sk, N, N, bias, bias2, relu,
                                              dF, ldF, dB, ldB);
        }
    };
    // LN site: GEMM(N=1024) partials -> reduce_ln (bias + residual + LN)
    auto site_ln = [&](const unsigned short* A, long lda, const unsigned short* Wt,
                       int Kd, int M, const float* bias,
                       const float* resid, long ldres,
                       const float* g_, const float* b_,
                       float* oF, long ldoF, unsigned short* oB, long ldoB) {
        const int sk = pick_sk(M, 1024, Kd, DSCRCAP);
        const long ps = (long)M * 1024;
        dim3 g(1024 >> 7, M >> 7, sk);
        gemm_bf16_lds<<<g, 256, 0, stream>>>(A, (int)lda, Wt, Kd,
            dscr, 1024, ps, nullptr, 0, nullptr, nullptr, Kd / sk, 0, 1);
        reduce_ln<<<M, 256, 0, stream>>>(dscr, ps, sk, bias, resid, ldres,
                                         g_, b_, oF, ldoF, oB, ldoB);
    };
    auto attn = [&](const float* qp, const float* kp, const float* vp,
                    float* opf, unsigned short* opb,
                    long q_bs, long q_ts, long kv_bs, long kv_ts,
                    long o_bs, long o_ts, int nq, int nk, int causal) {
        dim3 g(B_ * H_, nq);
        attn64<<<g, 64, 0, stream>>>(qp, kp, vp, opf, opb, H_, q_bs, q_ts, kv_bs, kv_ts,
                                     o_bs, o_ts, nk, causal, 0.125f);
    };
    auto conv = [&](const float* s, unsigned short* d, long n) {
        const long n4 = n >> 2;
        convert_f2bf<<<(int)((n4 + 255) >> 8), 256, 0, stream>>>(s, d, n4);
    };

    // ---- weight conversions (decoder path only) ----
    conv(dec_sa_qkv_w, wb_sa_qkv, (long)L_ * 3 * D_ * D_);
    conv(dec_sa_out_w, wb_sa_out, (long)L_ * D_ * D_);
    conv(dec_ca_qkv_w, wb_ca_qkv, (long)L_ * 3 * D_ * D_);
    conv(dec_ca_out_w, wb_ca_out, (long)L_ * D_ * D_);
    conv(dec_ff1_w,    wb_ff1,    (long)L_ * DFF_ * D_);
    conv(dec_ff2_w,    wb_ff2,    (long)L_ * D_ * DFF_);
    conv(rec_W,        wb_rec,    (long)S_ * D_);
    conv(enc_W,        wb_enc,    (long)D_ * S_);

    // ======================= Encoder (fp32 — idx exactness) =======================
    gemm(states, S_, enc_W, S_, D_, (int)NTOK, se, D_, enc_b, nullptr, 0);
    embed_add<<<(int)NTOK, 256, 0, stream>>>(se, actions, act_emb, pos_emb, xbuf);

    for (int i = 0; i < L_; ++i) {
        gemm(xbuf, D_, enc_qkv_w + (long)i * 3 * D_ * D_, D_, 3 * D_, (int)NTOK,
             big, 3 * D_, enc_qkv_b + (long)i * 3 * D_, nullptr, 0);
        attn(big, big + D_, big + 2 * D_, dq, nullptr,
             (long)T_ * 3 * D_, 3 * D_, (long)T_ * 3 * D_, 3 * D_,
             (long)T_ * D_, D_, T_, T_, 0);
        gemm(dq, D_, enc_out_w + (long)i * D_ * D_, D_, D_, (int)NTOK,
             enc_bufb, D_, enc_out_b + i * D_, nullptr, 0);
        ln_res<<<(int)NTOK, 256, 0, stream>>>(xbuf, enc_bufb, enc_ln1_g + i * D_,
                                              enc_ln1_b + i * D_, xbuf, nullptr);
        gemm(xbuf, D_, enc_ff1_w + (long)i * DFF_ * D_, D_, DFF_, (int)NTOK,
             big, DFF_, enc_ff1_b + i * DFF_, nullptr, 1);
        gemm(big, DFF_, enc_ff2_w + (long)i * D_ * DFF_, DFF_, D_, (int)NTOK,
             enc_bufb, D_, enc_ff2_b + i * D_, nullptr, 0);
        ln_res<<<(int)NTOK, 256, 0, stream>>>(xbuf, enc_bufb, enc_ln2_g + i * D_,
                                              enc_ln2_b + i * D_, xbuf, nullptr);
    }

    // ======================= VQ (fp32, numpy order) =======================
    row_sumsq<<<KC_, 256, 0, stream>>>(codebook, c2);
    gemm(xbuf, D_, codebook, D_, KC_, (int)NTOK, big, KC_, nullptr, nullptr, 0);
    vq_argmin<<<(int)NTOK, 256, 0, stream>>>(xbuf, big, c2, idx_i, idx_out);
    quant_build<<<(int)NTOK, 256, 0, stream>>>(idx_i, codebook, quant, bf_q);
    zero_f<<<1, 1, 0, stream>>>(accum);
    sq_diff_partial<<<(int)NTOK, 256, 0, stream>>>(xbuf, quant, accum);
    loss_final<<<1, 1, 0, stream>>>(accum, loss_out);

    // ============ Decoder: precompute cross-attn K/V (bf16 MFMA) ============
    for (int i = 0; i < L_; ++i) {
        const unsigned short* wkv = wb_ca_qkv + (long)i * 3 * D_ * D_ + (long)D_ * D_;
        const float* bkv = dec_ca_qkv_b + (long)i * 3 * D_ + D_;
        site_eps(bf_q, D_, wkv, D_, 2 * D_, (int)NTOK, big, BIGCAP,
                 memKV + (long)i * NTOK * 2 * D_, 2 * D_, nullptr, 0,
                 bkv, nullptr, 0);
    }
    cur0_init<<<B_, 256, 0, stream>>>(se, pos_emb, cur);

    // ============ Decoder: 19 autoregressive steps ============
    for (int t = 0; t < T_ - 1; ++t) {
        const int P = t + 1;
        const int M = B_ * P;
        assemble_y<<<M, 256, 0, stream>>>(cur, ybuf, bf_y, P);

        // ---- layers 0..L-2: full prefix ----
        for (int i = 0; i < L_ - 1; ++i) {
            // causal self-attention
            site_eps(bf_y, D_, wb_sa_qkv + (long)i * 3 * D_ * D_, D_, 3 * D_, M,
                     big, BIGCAP, big, 3 * D_, nullptr, 0,
                     dec_sa_qkv_b + (long)i * 3 * D_, nullptr, 0);
            attn(big, big + D_, big + 2 * D_, nullptr, bf_a,
                 (long)P * 3 * D_, 3 * D_, (long)P * 3 * D_, 3 * D_,
                 (long)P * D_, D_, P, P, 1);
            site_ln(bf_a, D_, wb_sa_out + (long)i * D_ * D_, D_, M,
                    dec_sa_out_b + i * D_, ybuf, D_,
                    dec_ln1_g + i * D_, dec_ln1_b + i * D_, ybuf, D_, bf_y, D_);

            // cross-attention (memory fixed -> precomputed memKV)
            site_eps(bf_y, D_, wb_ca_qkv + (long)i * 3 * D_ * D_, D_, D_, M,
                     dscr, DSCRCAP, dq, D_, nullptr, 0,
                     dec_ca_qkv_b + (long)i * 3 * D_, nullptr, 0);
            const float* mkv = memKV + (long)i * NTOK * 2 * D_;
            attn(dq, mkv, mkv + D_, nullptr, bf_a,
                 (long)P * D_, D_, (long)T_ * 2 * D_, 2 * D_,
                 (long)P * D_, D_, P, P, 0);
            site_ln(bf_a, D_, wb_ca_out + (long)i * D_ * D_, D_, M,
                    dec_ca_out_b + i * D_, ybuf, D_,
                    dec_ln2_g + i * D_, dec_ln2_b + i * D_, ybuf, D_, bf_y, D_);

            // FFN
            site_eps(bf_y, D_, wb_ff1 + (long)i * DFF_ * D_, D_, DFF_, M,
                     big, BIGCAP, nullptr, 0, bf_big, DFF_,
                     dec_ff1_b + i * DFF_, nullptr, 1);
            site_ln(bf_big, DFF_, wb_ff2 + (long)i * D_ * DFF_, DFF_, M,
                    dec_ff2_b + i * D_, ybuf, D_,
                    dec_ln3_g + i * D_, dec_ln3_b + i * D_, ybuf, D_, bf_y, D_);
        }

        // ---- layer L-1: only the last position is needed downstream ----
        {
            const int i = L_ - 1;
            gather_last<<<B_, 256, 0, stream>>>(ybuf, P, ysm, bf_ysm);

            // self-attn K,V over full prefix (N=2048), Q only for last pos
            site_eps(bf_y, D_, wb_sa_qkv + (long)i * 3 * D_ * D_ + (long)D_ * D_,
                     D_, 2 * D_, M, big, BIGCAP, big, 2 * D_, nullptr, 0,
                     dec_sa_qkv_b + (long)i * 3 * D_ + D_, nullptr, 0);
            site_eps(bf_ysm, D_, wb_sa_qkv + (long)i * 3 * D_ * D_, D_, D_, B_,
                     dscr, DSCRCAP, dq, D_, nullptr, 0,
                     dec_sa_qkv_b + (long)i * 3 * D_, nullptr, 0);
            attn(dq, big, big + D_, nullptr, bf_a,
                 (long)D_, 0, (long)P * 2 * D_, 2 * D_,
                 (long)D_, 0, 1, P, 0);
            site_ln(bf_a, D_, wb_sa_out + (long)i * D_ * D_, D_, B_,
                    dec_sa_out_b + i * D_, ysm, D_,
                    dec_ln1_g + i * D_, dec_ln1_b + i * D_, ysm, D_, bf_ysm, D_);

            // cross-attn (last pos only)
            site_eps(bf_ysm, D_, wb_ca_qkv + (long)i * 3 * D_ * D_, D_, D_, B_,
                     dscr, DSCRCAP, dq, D_, nullptr, 0,
                     dec_ca_qkv_b + (long)i * 3 * D_, nullptr, 0);
            const float* mkv = memKV + (long)i * NTOK * 2 * D_;
            attn(dq, mkv, mkv + D_, nullptr, bf_a,
                 (long)D_, 0, (long)T_ * 2 * D_, 2 * D_,
                 (long)D_, 0, 1, P, 0);
            site_ln(bf_a, D_, wb_ca_out + (long)i * D_ * D_, D_, B_,
                    dec_ca_out_b + i * D_, ysm, D_,
                    dec_ln2_g + i * D_, dec_ln2_b + i * D_, ysm, D_, bf_ysm, D_);

            // FFN (last pos only)
            site_eps(bf_ysm, D_, wb_ff1 + (long)i * DFF_ * D_, D_, DFF_, B_,
                     big, BIGCAP, nullptr, 0, bf_big, DFF_,
                     dec_ff1_b + i * DFF_, nullptr, 1);
            site_ln(bf_big, DFF_, wb_ff2 + (long)i * D_ * DFF_, DFF_, B_,
                    dec_ff2_b + i * D_, ysm, D_,
                    dec_ln3_g + i * D_, dec_ln3_b + i * D_, ysm, D_, bf_ysm, D_);
        }

        // preds[t] = y_last @ rec_W^T + rec_b  -> pred[:, t, :]  (strided C)
        site_eps(bf_ysm, D_, wb_rec, D_, S_, B_, dscr, DSCRCAP,
                 pred + (long)t * S_, (long)(T_ - 1) * S_,
                 (t < T_ - 2) ? bf_p : nullptr, S_,
                 rec_b, nullptr, 0);

        // dec_in[:, t+1] = preds[t] @ enc_W^T + enc_b + pos_emb[t+1]  (strided C)
        if (t < T_ - 2)
            site_eps(bf_p, S_, wb_enc, S_, D_, B_, dscr, DSCRCAP,
                     cur + (long)(t + 1) * D_, (long)T_ * D_, nullptr, 0,
                     enc_b, pos_emb + (long)(t + 1) * D_, 0);
    }
}

// Round 3
// 16541.795 us; speedup vs baseline: 2.4809x; 1.2692x over previous
//
#include <hip/hip_runtime.h>
#include <math.h>

// Problem constants
#define B_   128
#define T_   20
#define S_   512
#define D_   1024
#define H_   16
#define L_   4
#define KC_  2048   // codebook size
#define DFF_ 4096

typedef __attribute__((ext_vector_type(8))) short bf16x8;   // 8 bf16 (4 VGPRs)
typedef __attribute__((ext_vector_type(4))) float f32x4;

__device__ __forceinline__ unsigned short f2bf_rne(float f) {
    unsigned u = __float_as_uint(f);
    u += 0x7fffu + ((u >> 16) & 1u);
    return (unsigned short)(u >> 16);
}
__device__ __forceinline__ unsigned pack2(float a, float b) {
    return (unsigned)f2bf_rne(a) | ((unsigned)f2bf_rne(b) << 16);
}

// async global->LDS, 16B per lane; LDS dest is wave-uniform base + lane*16
__device__ __forceinline__ void gload16(const unsigned short* g, unsigned short* l)
{
    __builtin_amdgcn_global_load_lds(
        (const __attribute__((address_space(1))) unsigned int*)g,
        (__attribute__((address_space(3))) unsigned int*)l,
        16, 0, 0);
}

// ---------------------------------------------------------------------------
// fp32 GEMM (encoder + VQ path — bit-stable, idx exactness):
// C[M,N] = A[M,K] * W[N,K]^T (+bias)(+bias2)(+relu); M%128==0, N%128==0, K%16==0
// ---------------------------------------------------------------------------
__global__ __launch_bounds__(256, 2)
void gemm_nt(const float* __restrict__ A, int lda,
             const float* __restrict__ W, int ldb,
             float* __restrict__ C, int ldc,
             const float* __restrict__ bias,
             const float* __restrict__ bias2,
             int Kd, int relu)
{
    __shared__ float As[16][132];
    __shared__ float Bs[16][132];
    const int tid = threadIdx.x;
    const int m0 = blockIdx.y << 7;
    const int n0 = blockIdx.x << 7;
    const int tx = tid & 15;
    const int ty = tid >> 4;

    float acc[2][2][4][4];
#pragma unroll
    for (int a = 0; a < 2; ++a)
#pragma unroll
        for (int b = 0; b < 2; ++b)
#pragma unroll
            for (int i = 0; i < 4; ++i)
#pragma unroll
                for (int j = 0; j < 4; ++j) acc[a][b][i][j] = 0.f;

    const int lrow = tid >> 2;
    const int lkk  = (tid & 3) << 2;
    const float* Ap0 = A + (long)(m0 + lrow)      * lda + lkk;
    const float* Ap1 = A + (long)(m0 + lrow + 64) * lda + lkk;
    const float* Bp0 = W + (long)(n0 + lrow)      * ldb + lkk;
    const float* Bp1 = W + (long)(n0 + lrow + 64) * ldb + lkk;

    for (int k0 = 0; k0 < Kd; k0 += 16) {
        const float4 a0 = *(const float4*)(Ap0 + k0);
        const float4 a1 = *(const float4*)(Ap1 + k0);
        const float4 b0 = *(const float4*)(Bp0 + k0);
        const float4 b1 = *(const float4*)(Bp1 + k0);
        __syncthreads();
        As[lkk + 0][lrow] = a0.x; As[lkk + 1][lrow] = a0.y;
        As[lkk + 2][lrow] = a0.z; As[lkk + 3][lrow] = a0.w;
        As[lkk + 0][lrow + 64] = a1.x; As[lkk + 1][lrow + 64] = a1.y;
        As[lkk + 2][lrow + 64] = a1.z; As[lkk + 3][lrow + 64] = a1.w;
        Bs[lkk + 0][lrow] = b0.x; Bs[lkk + 1][lrow] = b0.y;
        Bs[lkk + 2][lrow] = b0.z; Bs[lkk + 3][lrow] = b0.w;
        Bs[lkk + 0][lrow + 64] = b1.x; Bs[lkk + 1][lrow + 64] = b1.y;
        Bs[lkk + 2][lrow + 64] = b1.z; Bs[lkk + 3][lrow + 64] = b1.w;
        __syncthreads();
#pragma unroll
        for (int kk = 0; kk < 16; ++kk) {
            const float4 aLo = *(const float4*)&As[kk][ty << 2];
            const float4 aHi = *(const float4*)&As[kk][(ty << 2) + 64];
            const float4 bLo = *(const float4*)&Bs[kk][tx << 2];
            const float4 bHi = *(const float4*)&Bs[kk][(tx << 2) + 64];
            const float am[2][4] = {{aLo.x, aLo.y, aLo.z, aLo.w},
                                    {aHi.x, aHi.y, aHi.z, aHi.w}};
            const float bn[2][4] = {{bLo.x, bLo.y, bLo.z, bLo.w},
                                    {bHi.x, bHi.y, bHi.z, bHi.w}};
#pragma unroll
            for (int mi = 0; mi < 2; ++mi)
#pragma unroll
                for (int i = 0; i < 4; ++i) {
                    const float av = am[mi][i];
#pragma unroll
                    for (int ni = 0; ni < 2; ++ni) {
                        acc[mi][ni][i][0] += av * bn[ni][0];
                        acc[mi][ni][i][1] += av * bn[ni][1];
                        acc[mi][ni][i][2] += av * bn[ni][2];
                        acc[mi][ni][i][3] += av * bn[ni][3];
                    }
                }
        }
    }

#pragma unroll
    for (int mi = 0; mi < 2; ++mi)
#pragma unroll
        for (int i = 0; i < 4; ++i) {
            const int m = m0 + (mi << 6) + (ty << 2) + i;
            float* crow = C + (long)m * ldc + n0;
#pragma unroll
            for (int ni = 0; ni < 2; ++ni) {
                const int n = (ni << 6) + (tx << 2);
                float4 v = make_float4(acc[mi][ni][i][0], acc[mi][ni][i][1],
                                       acc[mi][ni][i][2], acc[mi][ni][i][3]);
                if (bias) {
                    v.x += bias[n0 + n];     v.y += bias[n0 + n + 1];
                    v.z += bias[n0 + n + 2]; v.w += bias[n0 + n + 3];
                }
                if (bias2) {
                    v.x += bias2[n0 + n];     v.y += bias2[n0 + n + 1];
                    v.z += bias2[n0 + n + 2]; v.w += bias2[n0 + n + 3];
                }
                if (relu) {
                    v.x = fmaxf(v.x, 0.f); v.y = fmaxf(v.y, 0.f);
                    v.z = fmaxf(v.z, 0.f); v.w = fmaxf(v.w, 0.f);
                }
                *(float4*)(crow + n) = v;
            }
        }
}

// ---------------------------------------------------------------------------
// bf16 MFMA GEMM (m97-structure): C[M,N] = A_bf16[M,K] * Wbf16[N,K]^T
// 128x128 tile, BK=64, 4 waves, linear LDS, global_load_lds w=16.
// pmode=1: store raw fp32 partial of K-slice z at Cf + z*pstride + m*ldc + n
// pmode=0: (grid.z==1) direct epilogue: +bias(+bias2)(+relu), write Cf/Cb.
// M%128==0, N%128==0, ksl%64==0, lda/ldb %8 (16B rows).
// Fragment + C/D layouts per learn_hip m89/m91 (verified rounds 1-3).
// ---------------------------------------------------------------------------
__global__ __launch_bounds__(256, 2)
void gemm_bf16_lds(const unsigned short* __restrict__ A, int lda,
                   const unsigned short* __restrict__ W, int ldb,
                   float* __restrict__ Cf, int ldc, long pstride,
                   unsigned short* __restrict__ Cb, int ldcb,
                   const float* __restrict__ bias,
                   const float* __restrict__ bias2,
                   int ksl, int relu, int pmode)
{
    __shared__ __align__(16) unsigned short As[128 * 64];
    __shared__ __align__(16) unsigned short Bs[128 * 64];
    const int tid  = threadIdx.x;
    const int wave = tid >> 6;
    const int lane = tid & 63;
    const int m0 = blockIdx.y << 7;
    const int n0 = blockIdx.x << 7;
    const int kbeg = blockIdx.z * ksl;
    const int wm = (wave >> 1) << 6;    // 0 / 64
    const int wn = (wave & 1) << 6;     // 0 / 64
    const int lrow = lane & 15;
    const int q = lane >> 4;

    const unsigned short* Ag[4];
    const unsigned short* Wg[4];
    unsigned short* Al[4];
    unsigned short* Bl[4];
#pragma unroll
    for (int i = 0; i < 4; ++i) {
        const int blk = (wave << 2) + i;          // 0..15
        const int bo  = (blk << 10) + (lane << 4);
        const int r   = bo >> 7;
        const int ce  = (bo & 127) >> 1;
        Ag[i] = A + (long)(m0 + r) * lda + kbeg + ce;
        Wg[i] = W + (long)(n0 + r) * ldb + kbeg + ce;
        Al[i] = As + (blk << 9);                  // wave-uniform LDS base
        Bl[i] = Bs + (blk << 9);
    }

    f32x4 acc[4][4];
#pragma unroll
    for (int i = 0; i < 4; ++i)
#pragma unroll
        for (int j = 0; j < 4; ++j) acc[i][j] = (f32x4){0.f, 0.f, 0.f, 0.f};

    for (int k0 = 0; k0 < ksl; k0 += 64) {
        __syncthreads();
#pragma unroll
        for (int i = 0; i < 4; ++i) gload16(Ag[i] + k0, Al[i]);
#pragma unroll
        for (int i = 0; i < 4; ++i) gload16(Wg[i] + k0, Bl[i]);
        __syncthreads();

#pragma unroll
        for (int kk = 0; kk < 2; ++kk) {
            bf16x8 af[4], bfr[4];
#pragma unroll
            for (int mi = 0; mi < 4; ++mi)
                af[mi] = *(const bf16x8*)&As[(wm + mi * 16 + lrow) * 64 + kk * 32 + q * 8];
#pragma unroll
            for (int ni = 0; ni < 4; ++ni)
                bfr[ni] = *(const bf16x8*)&Bs[(wn + ni * 16 + lrow) * 64 + kk * 32 + q * 8];
#pragma unroll
            for (int mi = 0; mi < 4; ++mi)
#pragma unroll
                for (int ni = 0; ni < 4; ++ni)
                    acc[mi][ni] = __builtin_amdgcn_mfma_f32_16x16x32_bf16(
                        af[mi], bfr[ni], acc[mi][ni], 0, 0, 0);
        }
    }

    // C/D layout: col = lane&15, row = (lane>>4)*4 + reg   [m89/m91]
    if (pmode) {
        float* pbase = Cf + (long)blockIdx.z * pstride;
#pragma unroll
        for (int mi = 0; mi < 4; ++mi) {
#pragma unroll
            for (int r = 0; r < 4; ++r) {
                const int m = m0 + wm + mi * 16 + q * 4 + r;
                float* crow = pbase + (long)m * ldc;
#pragma unroll
                for (int ni = 0; ni < 4; ++ni)
                    crow[n0 + wn + ni * 16 + lrow] = acc[mi][ni][r];
            }
        }
    } else {
#pragma unroll
        for (int mi = 0; mi < 4; ++mi) {
#pragma unroll
            for (int r = 0; r < 4; ++r) {
                const int m = m0 + wm + mi * 16 + q * 4 + r;
#pragma unroll
                for (int ni = 0; ni < 4; ++ni) {
                    const int n = n0 + wn + ni * 16 + lrow;
                    float v = acc[mi][ni][r];
                    if (bias)  v += bias[n];
                    if (bias2) v += bias2[n];
                    if (relu)  v = fmaxf(v, 0.f);
                    if (Cf) Cf[(long)m * ldc + n] = v;
                    if (Cb) Cb[(long)m * ldcb + n] = f2bf_rne(v);
                }
            }
        }
    }
}

// ---------------------------------------------------------------------------
// reduce_eps: sum sk partial slices + bias(+bias2)(+relu) -> fp32/bf16 dests.
// grid.x = M rows, 256 threads, 4 cols/thread/iter.
// ---------------------------------------------------------------------------
__global__ __launch_bounds__(256)
void reduce_eps(const float* __restrict__ Pt, long pstride, int sk, int pld,
                int ncols,
                const float* __restrict__ bias, const float* __restrict__ bias2,
                int relu,
                float* __restrict__ dF, long ldF,
                unsigned short* __restrict__ dB, long ldB)
{
    const int r = blockIdx.x;
    const float* pr = Pt + (long)r * pld;
    for (int c = (threadIdx.x << 2); c < ncols; c += 1024) {
        float4 s = *(const float4*)(pr + c);
        for (int z = 1; z < sk; ++z) {
            const float4 v = *(const float4*)(pr + (long)z * pstride + c);
            s.x += v.x; s.y += v.y; s.z += v.z; s.w += v.w;
        }
        if (bias) {
            const float4 b = *(const float4*)(bias + c);
            s.x += b.x; s.y += b.y; s.z += b.z; s.w += b.w;
        }
        if (bias2) {
            const float4 b = *(const float4*)(bias2 + c);
            s.x += b.x; s.y += b.y; s.z += b.z; s.w += b.w;
        }
        if (relu) {
            s.x = fmaxf(s.x, 0.f); s.y = fmaxf(s.y, 0.f);
            s.z = fmaxf(s.z, 0.f); s.w = fmaxf(s.w, 0.f);
        }
        if (dF) *(float4*)(dF + (long)r * ldF + c) = s;
        if (dB) {
            uint2 o; o.x = pack2(s.x, s.y); o.y = pack2(s.z, s.w);
            *(uint2*)(dB + (long)r * ldB + c) = o;
        }
    }
}

// ---------------------------------------------------------------------------
// reduce_ln: sum sk partial slices (pld=1024) + bias, add residual row,
// LayerNorm(D=1024) with gamma/beta, write fp32 + bf16.
// ---------------------------------------------------------------------------
__global__ __launch_bounds__(256)
void reduce_ln(const float* __restrict__ Pt, long pstride, int sk,
               const float* __restrict__ bias,
               const float* __restrict__ resid, long ldres,
               const float* __restrict__ g, const float* __restrict__ bta,
               float* __restrict__ outF, long ldoF,
               unsigned short* __restrict__ outB, long ldoB)
{
    __shared__ float red[4];
    const int r = blockIdx.x, tid = threadIdx.x;
    const int c = tid << 2;
    const float* pr = Pt + (long)r * 1024 + c;
    float4 s = *(const float4*)pr;
    for (int z = 1; z < sk; ++z) {
        const float4 v = *(const float4*)(pr + (long)z * pstride);
        s.x += v.x; s.y += v.y; s.z += v.z; s.w += v.w;
    }
    const float4 bb = *(const float4*)(bias + c);
    const float4 rv = *(const float4*)(resid + (long)r * ldres + c);
    const float v0 = s.x + bb.x + rv.x, v1 = s.y + bb.y + rv.y;
    const float v2 = s.z + bb.z + rv.z, v3 = s.w + bb.w + rv.w;

    float sm = v0 + v1 + v2 + v3;
#pragma unroll
    for (int off = 32; off >= 1; off >>= 1) sm += __shfl_xor(sm, off);
    const int wid = tid >> 6, lane = tid & 63;
    if (lane == 0) red[wid] = sm;
    __syncthreads();
    const float mean = (red[0] + red[1] + red[2] + red[3]) * (1.f / D_);
    __syncthreads();

    const float d0 = v0 - mean, d1 = v1 - mean, d2 = v2 - mean, d3 = v3 - mean;
    float s2 = d0 * d0 + d1 * d1 + d2 * d2 + d3 * d3;
#pragma unroll
    for (int off = 32; off >= 1; off >>= 1) s2 += __shfl_xor(s2, off);
    if (lane == 0) red[wid] = s2;
    __syncthreads();
    const float var = (red[0] + red[1] + red[2] + red[3]) * (1.f / D_);
    const float rs = 1.f / sqrtf(var + 1e-5f);

    const float4 gv = *(const float4*)(g + c);
    const float4 bv = *(const float4*)(bta + c);
    float4 o;
    o.x = d0 * rs * gv.x + bv.x; o.y = d1 * rs * gv.y + bv.y;
    o.z = d2 * rs * gv.z + bv.z; o.w = d3 * rs * gv.w + bv.w;
    *(float4*)(outF + (long)r * ldoF + c) = o;
    uint2 ov; ov.x = pack2(o.x, o.y); ov.y = pack2(o.z, o.w);
    *(uint2*)(outB + (long)r * ldoB + c) = ov;
}

// fp32 -> bf16 (RNE) bulk convert; n4 = n/4 float4 groups
__global__ __launch_bounds__(256)
void convert_f2bf(const float* __restrict__ src, unsigned short* __restrict__ dst, long n4)
{
    const long i = (long)blockIdx.x * 256 + threadIdx.x;
    if (i < n4) {
        const float4 v = ((const float4*)src)[i];
        uint2 o;
        o.x = pack2(v.x, v.y);
        o.y = pack2(v.z, v.w);
        ((uint2*)dst)[i] = o;
    }
}

// ---------------------------------------------------------------------------
// Attention for hd=64: one wave per (b, h, query-pos). nkeys <= 20.
// Q may be given as qsum split-K partial slices (stride q_ps) + qbias.
// Writes fp32 (opf) and/or bf16 (opb) output, same strides.
// ---------------------------------------------------------------------------
__global__ __launch_bounds__(64)
void attn64(const float* __restrict__ qp, int qsum, long q_ps,
            const float* __restrict__ qbias,
            const float* __restrict__ kp, const float* __restrict__ vp,
            float* __restrict__ opf, unsigned short* __restrict__ opb,
            int H, long q_bs, long q_ts, long kv_bs, long kv_ts,
            long o_bs, long o_ts, int nk, int causal, float scale)
{
    const int b  = blockIdx.x / H;
    const int h  = blockIdx.x % H;
    const int qj = blockIdx.y;
    const int tid = threadIdx.x;
    __shared__ float sc[32];

    const long qoff = (long)b * q_bs + (long)qj * q_ts + h * 64 + tid;
    float qv = qp[qoff];
    for (int z = 1; z < qsum; ++z) qv += qp[qoff + (long)z * q_ps];
    if (qbias) qv += qbias[h * 64 + tid];

    const int nkeys = causal ? (qj + 1) : nk;
    const long kbase = (long)b * kv_bs + h * 64 + tid;

    for (int j = 0; j < nkeys; ++j) {
        float p = qv * kp[kbase + (long)j * kv_ts];
#pragma unroll
        for (int off = 32; off >= 1; off >>= 1) p += __shfl_xor(p, off);
        if (tid == 0) sc[j] = p * scale;
    }
    __syncthreads();

    const float sval = (tid < nkeys) ? sc[tid] : -INFINITY;
    float mx = sval;
#pragma unroll
    for (int off = 32; off >= 1; off >>= 1) mx = fmaxf(mx, __shfl_xor(mx, off));
    const float e = (tid < nkeys) ? expf(sval - mx) : 0.f;
    float ssum = e;
#pragma unroll
    for (int off = 32; off >= 1; off >>= 1) ssum += __shfl_xor(ssum, off);
    if (tid < nkeys) sc[tid] = e / ssum;
    __syncthreads();

    float acc = 0.f;
    for (int j = 0; j < nkeys; ++j) acc += sc[j] * vp[kbase + (long)j * kv_ts];
    const long ob = (long)b * o_bs + (long)qj * o_ts + h * 64 + tid;
    if (opf) opf[ob] = acc;
    if (opb) opb[ob] = f2bf_rne(acc);
}

// ---------------------------------------------------------------------------
// LayerNorm with residual (encoder path)
// ---------------------------------------------------------------------------
__global__ __launch_bounds__(256)
void ln_res(const float* __restrict__ x, const float* __restrict__ hh,
            const float* __restrict__ g, const float* __restrict__ bta,
            float* __restrict__ out)
{
    __shared__ float red[4];
    const int r = blockIdx.x, tid = threadIdx.x;
    const long base = (long)r * D_ + (tid << 2);
    const float4 xv = *(const float4*)(x + base);
    const float4 hv = *(const float4*)(hh + base);
    const float v0 = xv.x + hv.x, v1 = xv.y + hv.y, v2 = xv.z + hv.z, v3 = xv.w + hv.w;

    float s = v0 + v1 + v2 + v3;
#pragma unroll
    for (int off = 32; off >= 1; off >>= 1) s += __shfl_xor(s, off);
    const int wid = tid >> 6, lane = tid & 63;
    if (lane == 0) red[wid] = s;
    __syncthreads();
    const float mean = (red[0] + red[1] + red[2] + red[3]) * (1.f / D_);
    __syncthreads();

    const float d0 = v0 - mean, d1 = v1 - mean, d2 = v2 - mean, d3 = v3 - mean;
    float s2 = d0 * d0 + d1 * d1 + d2 * d2 + d3 * d3;
#pragma unroll
    for (int off = 32; off >= 1; off >>= 1) s2 += __shfl_xor(s2, off);
    if (lane == 0) red[wid] = s2;
    __syncthreads();
    const float var = (red[0] + red[1] + red[2] + red[3]) * (1.f / D_);
    const float rs = 1.f / sqrtf(var + 1e-5f);

    const float4 gv = *(const float4*)(g + (tid << 2));
    const float4 bv = *(const float4*)(bta + (tid << 2));
    float4 o;
    o.x = d0 * rs * gv.x + bv.x; o.y = d1 * rs * gv.y + bv.y;
    o.z = d2 * rs * gv.z + bv.z; o.w = d3 * rs * gv.w + bv.w;
    *(float4*)(out + base) = o;
}

__global__ void embed_add(const float* __restrict__ se, const int* __restrict__ actions,
                          const float* __restrict__ act_emb, const float* __restrict__ pos,
                          float* __restrict__ x)
{
    const int r = blockIdx.x, c = threadIdx.x << 2;
    const int t = r % T_;
    const int a = actions[r];
    const float4 sv = *(const float4*)(se + (long)r * D_ + c);
    const float4 av = *(const float4*)(act_emb + (long)a * D_ + c);
    const float4 pv = *(const float4*)(pos + (long)t * D_ + c);
    float4 o;
    o.x = sv.x + av.x + pv.x; o.y = sv.y + av.y + pv.y;
    o.z = sv.z + av.z + pv.z; o.w = sv.w + av.w + pv.w;
    *(float4*)(x + (long)r * D_ + c) = o;
}

// ysm[b] = se[b, 0] + pos_emb[0]  (decoder step-0 input)
__global__ void ysm_init(const float* __restrict__ se, const float* __restrict__ pos,
                         float* __restrict__ ysm, unsigned short* __restrict__ yb)
{
    const int b = blockIdx.x, c = threadIdx.x << 2;
    const float4 sv = *(const float4*)(se + (long)b * T_ * D_ + c);
    const float4 pv = *(const float4*)(pos + c);
    float4 o; o.x = sv.x + pv.x; o.y = sv.y + pv.y; o.z = sv.z + pv.z; o.w = sv.w + pv.w;
    *(float4*)(ysm + (long)b * D_ + c) = o;
    uint2 ov; ov.x = pack2(o.x, o.y); ov.y = pack2(o.z, o.w);
    *(uint2*)(yb + (long)b * D_ + c) = ov;
}

__global__ void quant_build(const int* __restrict__ idx, const float* __restrict__ cb,
                            float* __restrict__ quant, unsigned short* __restrict__ qb)
{
    const int r = blockIdx.x, c = threadIdx.x << 2;
    const int code = idx[r];
    const float4 v = *(const float4*)(cb + (long)code * D_ + c);
    *(float4*)(quant + (long)r * D_ + c) = v;
    uint2 o; o.x = pack2(v.x, v.y); o.y = pack2(v.z, v.w);
    *(uint2*)(qb + (long)r * D_ + c) = o;
}

__global__ __launch_bounds__(256)
void row_sumsq(const float* __restrict__ A, float* __restrict__ out)
{
    __shared__ float red[4];
    const int r = blockIdx.x, tid = threadIdx.x;
    const float4 v = *(const float4*)(A + (long)r * D_ + (tid << 2));
    float s = v.x * v.x + v.y * v.y + v.z * v.z + v.w * v.w;
#pragma unroll
    for (int off = 32; off >= 1; off >>= 1) s += __shfl_xor(s, off);
    const int wid = tid >> 6, lane = tid & 63;
    if (lane == 0) red[wid] = s;
    __syncthreads();
    if (tid == 0) out[r] = red[0] + red[1] + red[2] + red[3];
}

__global__ __launch_bounds__(256)
void vq_argmin(const float* __restrict__ x, const float* __restrict__ dot,
               const float* __restrict__ c2, int* __restrict__ idx_i,
               float* __restrict__ idx_f)
{
    __shared__ float red[4];
    __shared__ float redv[4];
    __shared__ int   redi[4];
    const int r = blockIdx.x, tid = threadIdx.x;
    const float4 v = *(const float4*)(x + (long)r * D_ + (tid << 2));
    float s = v.x * v.x + v.y * v.y + v.z * v.z + v.w * v.w;
#pragma unroll
    for (int off = 32; off >= 1; off >>= 1) s += __shfl_xor(s, off);
    const int wid = tid >> 6, lane = tid & 63;
    if (lane == 0) red[wid] = s;
    __syncthreads();
    const float a = red[0] + red[1] + red[2] + red[3];

    float best = 3.4e38f; int bidx = 0;
    const float* dr = dot + (long)r * KC_;
    for (int j = tid; j < KC_; j += 256) {
        const float d = (a - 2.f * dr[j]) + c2[j];
        if (d < best) { best = d; bidx = j; }
    }
#pragma unroll
    for (int off = 32; off >= 1; off >>= 1) {
        const float ob = __shfl_xor(best, off);
        const int   oi = __shfl_xor(bidx, off);
        if (ob < best || (ob == best && oi < bidx)) { best = ob; bidx = oi; }
    }
    if (lane == 0) { redv[wid] = best; redi[wid] = bidx; }
    __syncthreads();
    if (tid == 0) {
        for (int w2 = 1; w2 < 4; ++w2)
            if (redv[w2] < best || (redv[w2] == best && redi[w2] < bidx)) {
                best = redv[w2]; bidx = redi[w2];
            }
        idx_i[r] = bidx;
        idx_f[r] = (float)bidx;
    }
}

__global__ void zero_f(float* p) { p[0] = 0.f; }

__global__ __launch_bounds__(256)
void sq_diff_partial(const float* __restrict__ x, const float* __restrict__ q,
                     float* __restrict__ accum)
{
    __shared__ float red[4];
    const int r = blockIdx.x, tid = threadIdx.x;
    const long base = (long)r * D_ + (tid << 2);
    const float4 xv = *(const float4*)(x + base);
    const float4 qv = *(const float4*)(q + base);
    const float d0 = xv.x - qv.x, d1 = xv.y - qv.y, d2 = xv.z - qv.z, d3 = xv.w - qv.w;
    float s = d0 * d0 + d1 * d1 + d2 * d2 + d3 * d3;
#pragma unroll
    for (int off = 32; off >= 1; off >>= 1) s += __shfl_xor(s, off);
    const int wid = tid >> 6, lane = tid & 63;
    if (lane == 0) red[wid] = s;
    __syncthreads();
    if (tid == 0) atomicAdd(accum, red[0] + red[1] + red[2] + red[3]);
}

__global__ void loss_final(const float* __restrict__ accum, float* __restrict__ out)
{
    out[0] = 2.f * accum[0] * (1.f / (float)((long)B_ * T_ * D_));
}

// ---------------------------------------------------------------------------
extern "C" void kernel_launch(void* const* d_in, const int* in_sizes, int n_in,
                              void* d_out, int out_size, void* d_ws, size_t ws_size,
                              hipStream_t stream)
{
    const float* states      = (const float*)d_in[0];
    const int*   actions     = (const int*)  d_in[1];
    const float* enc_W       = (const float*)d_in[2];
    const float* enc_b       = (const float*)d_in[3];
    const float* act_emb     = (const float*)d_in[4];
    const float* pos_emb     = (const float*)d_in[5];
    const float* enc_qkv_w   = (const float*)d_in[6];
    const float* enc_qkv_b   = (const float*)d_in[7];
    const float* enc_out_w   = (const float*)d_in[8];
    const float* enc_out_b   = (const float*)d_in[9];
    const float* enc_ln1_g   = (const float*)d_in[10];
    const float* enc_ln1_b   = (const float*)d_in[11];
    const float* enc_ln2_g   = (const float*)d_in[12];
    const float* enc_ln2_b   = (const float*)d_in[13];
    const float* enc_ff1_w   = (const float*)d_in[14];
    const float* enc_ff1_b   = (const float*)d_in[15];
    const float* enc_ff2_w   = (const float*)d_in[16];
    const float* enc_ff2_b   = (const float*)d_in[17];
    const float* dec_sa_qkv_w= (const float*)d_in[18];
    const float* dec_sa_qkv_b= (const float*)d_in[19];
    const float* dec_sa_out_w= (const float*)d_in[20];
    const float* dec_sa_out_b= (const float*)d_in[21];
    const float* dec_ca_qkv_w= (const float*)d_in[22];
    const float* dec_ca_qkv_b= (const float*)d_in[23];
    const float* dec_ca_out_w= (const float*)d_in[24];
    const float* dec_ca_out_b= (const float*)d_in[25];
    const float* dec_ln1_g   = (const float*)d_in[26];
    const float* dec_ln1_b   = (const float*)d_in[27];
    const float* dec_ln2_g   = (const float*)d_in[28];
    const float* dec_ln2_b   = (const float*)d_in[29];
    const float* dec_ln3_g   = (const float*)d_in[30];
    const float* dec_ln3_b   = (const float*)d_in[31];
    const float* dec_ff1_w   = (const float*)d_in[32];
    const float* dec_ff1_b   = (const float*)d_in[33];
    const float* dec_ff2_w   = (const float*)d_in[34];
    const float* dec_ff2_b   = (const float*)d_in[35];
    const float* codebook    = (const float*)d_in[36];
    const float* rec_W       = (const float*)d_in[37];
    const float* rec_b       = (const float*)d_in[38];

    float* out      = (float*)d_out;
    float* pred     = out;                              // [128, 19, 512]
    float* loss_out = out + (long)B_ * (T_ - 1) * S_;
    float* idx_out  = loss_out + 1;

    const long NTOK = (long)B_ * T_;                    // 2560
    const long ROW  = NTOK * D_;                        // 2621440 floats
    const long SACL = (long)B_ * T_ * 2 * D_;           // per-layer SA cache (5.24M fl)

    // ---------------- workspace layout ----------------
    // Region R (9*ROW): encoder/VQ scratch. During decoding, sacache
    // (L*B*T*2D = 8*ROW exactly) aliases [big .. Rend).
    float* R    = (float*)d_ws;
    float* xbuf = R;                         // enc x
    float* big  = R + ROW;                   // 4*ROW: qkv/ff1/VQ-dot
    float* dq   = big + NTOK * DFF_;         // enc attn-out
    float* dscr = dq + ROW;                  // 3*ROW: enc bufb | quant | se
    float* enc_bufb = dscr;
    float* quant    = dscr + ROW;
    float* se       = dscr + 2 * ROW;
    float* sacache  = big;                   // decoder alias (8*ROW)

    float* memKV= dscr + 3 * ROW;            // L*NTOK*2D
    float* c2   = memKV + (long)L_ * NTOK * 2 * D_;
    float* accum= c2 + KC_;
    int*   idx_i= (int*)(accum + 1);
    float* dpart= (float*)(idx_i + NTOK);    // 6.3M floats (split-K partials)
    const long DPARTCAP = (long)16 * 128 * 3 * D_;      // 6291456
    float* ysm  = dpart + DPARTCAP;          // [128, D] decoder activation

    // bf16 weights + small activation mirrors
    unsigned short* wb = (unsigned short*)(ysm + (long)B_ * D_);
    unsigned short* wb_sa_qkv = wb;  wb += (long)L_ * 3 * D_ * D_;
    unsigned short* wb_sa_out = wb;  wb += (long)L_ * D_ * D_;
    unsigned short* wb_ca_qkv = wb;  wb += (long)L_ * 3 * D_ * D_;
    unsigned short* wb_ca_out = wb;  wb += (long)L_ * D_ * D_;
    unsigned short* wb_ff1    = wb;  wb += (long)L_ * DFF_ * D_;
    unsigned short* wb_ff2    = wb;  wb += (long)L_ * D_ * DFF_;
    unsigned short* wb_rec    = wb;  wb += (long)S_ * D_;
    unsigned short* wb_enc    = wb;  wb += (long)D_ * S_;
    unsigned short* bf_q      = wb;  wb += ROW;             // quant mirror
    unsigned short* bf_ysm    = wb;  wb += (long)B_ * D_;
    unsigned short* bf_a      = wb;  wb += (long)B_ * D_;   // attn out [128,1024]
    unsigned short* bf_h      = wb;  wb += (long)B_ * DFF_; // ff1 out [128,4096]
    unsigned short* bf_p      = wb;  wb += (long)B_ * S_;   // pred mirror
    const size_t need = (size_t)((char*)wb - (char*)d_ws);
    if (ws_size < need) return;  // fail loudly (output stays poisoned)

    auto gemm = [&](const float* A, int lda, const float* Wt, int Kd, int N, int M,
                    float* C, int ldc, const float* bias, const float* bias2, int relu) {
        dim3 g(N >> 7, M >> 7);
        gemm_nt<<<g, 256, 0, stream>>>(A, lda, Wt, Kd, C, ldc, bias, bias2, Kd, relu);
    };
    auto pick_sk = [&](int M, int N, int Kd) {
        const long base = (long)(M >> 7) * (N >> 7);
        int sk = 1;
        while (sk < 16) {
            const int nx = sk << 1;
            if (Kd % (64 * nx)) break;
            if (base * sk >= 256) break;
            if ((long)nx * M * N > DPARTCAP) break;
            sk = nx;
        }
        return sk;
    };
    // split-K GEMM into dpart (pmode=1); returns sk used
    auto gemmP = [&](const unsigned short* A, long lda, const unsigned short* Wt,
                     int Kd, int N, int M) {
        const int sk = pick_sk(M, N, Kd);
        dim3 g(N >> 7, M >> 7, sk);
        gemm_bf16_lds<<<g, 256, 0, stream>>>(A, (int)lda, Wt, Kd,
            dpart, N, (long)M * N, nullptr, 0, nullptr, nullptr, Kd / sk, 0, 1);
        return sk;
    };
    auto conv = [&](const float* s, unsigned short* d, long n) {
        const long n4 = n >> 2;
        convert_f2bf<<<(int)((n4 + 255) >> 8), 256, 0, stream>>>(s, d, n4);
    };

    // ---- weight conversions (decoder path only) ----
    conv(dec_sa_qkv_w, wb_sa_qkv, (long)L_ * 3 * D_ * D_);
    conv(dec_sa_out_w, wb_sa_out, (long)L_ * D_ * D_);
    conv(dec_ca_qkv_w, wb_ca_qkv, (long)L_ * 3 * D_ * D_);
    conv(dec_ca_out_w, wb_ca_out, (long)L_ * D_ * D_);
    conv(dec_ff1_w,    wb_ff1,    (long)L_ * DFF_ * D_);
    conv(dec_ff2_w,    wb_ff2,    (long)L_ * D_ * DFF_);
    conv(rec_W,        wb_rec,    (long)S_ * D_);
    conv(enc_W,        wb_enc,    (long)D_ * S_);

    // ======================= Encoder (fp32 — idx exactness) =======================
    gemm(states, S_, enc_W, S_, D_, (int)NTOK, se, D_, enc_b, nullptr, 0);
    embed_add<<<(int)NTOK, 256, 0, stream>>>(se, actions, act_emb, pos_emb, xbuf);

    for (int i = 0; i < L_; ++i) {
        gemm(xbuf, D_, enc_qkv_w + (long)i * 3 * D_ * D_, D_, 3 * D_, (int)NTOK,
             big, 3 * D_, enc_qkv_b + (long)i * 3 * D_, nullptr, 0);
        attn64<<<dim3(B_ * H_, T_), 64, 0, stream>>>(
            big, 1, 0, nullptr, big + D_, big + 2 * D_, dq, nullptr, H_,
            (long)T_ * 3 * D_, 3 * D_, (long)T_ * 3 * D_, 3 * D_,
            (long)T_ * D_, D_, T_, 0, 0.125f);
        gemm(dq, D_, enc_out_w + (long)i * D_ * D_, D_, D_, (int)NTOK,
             enc_bufb, D_, enc_out_b + i * D_, nullptr, 0);
        ln_res<<<(int)NTOK, 256, 0, stream>>>(xbuf, enc_bufb, enc_ln1_g + i * D_,
                                              enc_ln1_b + i * D_, xbuf);
        gemm(xbuf, D_, enc_ff1_w + (long)i * DFF_ * D_, D_, DFF_, (int)NTOK,
             big, DFF_, enc_ff1_b + i * DFF_, nullptr, 1);
        gemm(big, DFF_, enc_ff2_w + (long)i * D_ * DFF_, DFF_, D_, (int)NTOK,
             enc_bufb, D_, enc_ff2_b + i * D_, nullptr, 0);
        ln_res<<<(int)NTOK, 256, 0, stream>>>(xbuf, enc_bufb, enc_ln2_g + i * D_,
                                              enc_ln2_b + i * D_, xbuf);
    }

    // ======================= VQ (fp32, numpy order) =======================
    row_sumsq<<<KC_, 256, 0, stream>>>(codebook, c2);
    gemm(xbuf, D_, codebook, D_, KC_, (int)NTOK, big, KC_, nullptr, nullptr, 0);
    vq_argmin<<<(int)NTOK, 256, 0, stream>>>(xbuf, big, c2, idx_i, idx_out);
    quant_build<<<(int)NTOK, 256, 0, stream>>>(idx_i, codebook, quant, bf_q);
    zero_f<<<1, 1, 0, stream>>>(accum);
    sq_diff_partial<<<(int)NTOK, 256, 0, stream>>>(xbuf, quant, accum);
    loss_final<<<1, 1, 0, stream>>>(accum, loss_out);

    // ===== Decoder: precompute cross-attn K/V (M=2560 -> sk=1 direct) =====
    for (int i = 0; i < L_; ++i) {
        const unsigned short* wkv = wb_ca_qkv + (long)i * 3 * D_ * D_ + (long)D_ * D_;
        const float* bkv = dec_ca_qkv_b + (long)i * 3 * D_ + D_;
        dim3 g((2 * D_) >> 7, (int)NTOK >> 7, 1);
        gemm_bf16_lds<<<g, 256, 0, stream>>>(bf_q, D_, wkv, D_,
            memKV + (long)i * NTOK * 2 * D_, 2 * D_, 0, nullptr, 0,
            bkv, nullptr, D_, 0, 0);
    }
    // step-0 input: ysm = se[:,0] + pos_emb[0]   (reads se BEFORE sacache writes)
    ysm_init<<<B_, 256, 0, stream>>>(se, pos_emb, ysm, bf_ysm);

    // ===== Decoder: 19 incremental steps (KV-cached, M=128 everywhere) =====
    for (int t = 0; t < T_ - 1; ++t) {
        for (int i = 0; i < L_; ++i) {
            const float* bqkv = dec_sa_qkv_b + (long)i * 3 * D_;
            float* sac = sacache + (long)i * SACL;

            // --- fused QKV projection of the new position (partials) ---
            const int skq = gemmP(bf_ysm, D_, wb_sa_qkv + (long)i * 3 * D_ * D_,
                                  D_, 3 * D_, B_);
            // K,V (cols 1024..3071) reduced + bias into cache at position t
            reduce_eps<<<B_, 256, 0, stream>>>(dpart + D_, (long)B_ * 3 * D_, skq,
                3 * D_, 2 * D_, bqkv + D_, nullptr, 0,
                sac + (long)t * 2 * D_, (long)T_ * 2 * D_, nullptr, 0);
            // self-attn: new position vs cached keys 0..t (Q summed from partials)
            attn64<<<dim3(B_ * H_, 1), 64, 0, stream>>>(
                dpart, skq, (long)B_ * 3 * D_, bqkv,
                sac, sac + D_, nullptr, bf_a, H_,
                (long)3 * D_, 0, (long)T_ * 2 * D_, 2 * D_,
                (long)D_, 0, t + 1, 0, 0.125f);
            // out-proj + residual + LN1
            {
                const int sk = gemmP(bf_a, D_, wb_sa_out + (long)i * D_ * D_,
                                     D_, D_, B_);
                reduce_ln<<<B_, 256, 0, stream>>>(dpart, (long)B_ * D_, sk,
                    dec_sa_out_b + i * D_, ysm, D_,
                    dec_ln1_g + i * D_, dec_ln1_b + i * D_, ysm, D_, bf_ysm, D_);
            }

            // --- cross-attention (memory fixed -> precomputed memKV) ---
            {
                const int sk = gemmP(bf_ysm, D_, wb_ca_qkv + (long)i * 3 * D_ * D_,
                                     D_, D_, B_);
                const float* mkv = memKV + (long)i * NTOK * 2 * D_;
                attn64<<<dim3(B_ * H_, 1), 64, 0, stream>>>(
                    dpart, sk, (long)B_ * D_, dec_ca_qkv_b + (long)i * 3 * D_,
                    mkv, mkv + D_, nullptr, bf_a, H_,
                    (long)D_, 0, (long)T_ * 2 * D_, 2 * D_,
                    (long)D_, 0, T_, 0, 0.125f);
            }
            {
                const int sk = gemmP(bf_a, D_, wb_ca_out + (long)i * D_ * D_,
                                     D_, D_, B_);
                reduce_ln<<<B_, 256, 0, stream>>>(dpart, (long)B_ * D_, sk,
                    dec_ca_out_b + i * D_, ysm, D_,
                    dec_ln2_g + i * D_, dec_ln2_b + i * D_, ysm, D_, bf_ysm, D_);
            }

            // --- FFN ---
            {
                const int sk = gemmP(bf_ysm, D_, wb_ff1 + (long)i * DFF_ * D_,
                                     D_, DFF_, B_);
                reduce_eps<<<B_, 256, 0, stream>>>(dpart, (long)B_ * DFF_, sk,
                    DFF_, DFF_, dec_ff1_b + i * DFF_, nullptr, 1,
                    nullptr, 0, bf_h, DFF_);
            }
            {
                const int sk = gemmP(bf_h, DFF_, wb_ff2 + (long)i * D_ * DFF_,
                                     DFF_, D_, B_);
                reduce_ln<<<B_, 256, 0, stream>>>(dpart, (long)B_ * D_, sk,
                    dec_ff2_b + i * D_, ysm, D_,
                    dec_ln3_g + i * D_, dec_ln3_b + i * D_, ysm, D_, bf_ysm, D_);
            }
        }

        // preds[t] = ysm @ rec_W^T + rec_b -> pred[:, t, :] (strided)
        {
            const int sk = gemmP(bf_ysm, D_, wb_rec, D_, S_, B_);
            reduce_eps<<<B_, 256, 0, stream>>>(dpart, (long)B_ * S_, sk,
                S_, S_, rec_b, nullptr, 0,
                pred + (long)t * S_, (long)(T_ - 1) * S_,
                (t < T_ - 2) ? bf_p : nullptr, S_);
        }
        // next input: ysm = pred[t] @ enc_W^T + enc_b + pos_emb[t+1]
        if (t < T_ - 2) {
            const int sk = gemmP(bf_p, S_, wb_enc, S_, D_, B_);
            reduce_eps<<<B_, 256, 0, stream>>>(dpart, (long)B_ * D_, sk,
                D_, D_, enc_b, pos_emb + (long)(t + 1) * D_, 0,
                ysm, D_, bf_ysm, D_);
        }
    }
}